// Round 5
// baseline (416.931 us; speedup 1.0000x reference)
//
#include <hip/hip_runtime.h>
#include <hip/hip_bf16.h>
#include <math.h>

namespace {

typedef unsigned short u16;
typedef __bf16 bf16x8 __attribute__((ext_vector_type(8)));
typedef float f32x4 __attribute__((ext_vector_type(4)));

constexpr int L_SEQ  = 2048;
constexpr int DPROJ  = 2568;
constexpr int OFF_X  = 1024;
constexpr int OFF_B  = 2048;
constexpr int OFF_C  = 2304;
constexpr int OFF_DT = 2560;
constexpr int SCHUNK = 32;
constexpr int NCH    = L_SEQ / SCHUNK;  // 64

// ---------------------------------------------------------------------------
// f32 -> (bf16 hi, bf16 lo) split conversion. Pads rows to rows_pad w/ zeros.
// ---------------------------------------------------------------------------
__device__ inline u16 f2bf(float x) {
  unsigned u = __float_as_uint(x);
  unsigned r = u + 0x7FFFu + ((u >> 16) & 1u);
  return (u16)(r >> 16);
}

__global__ __launch_bounds__(256)
void convert_split(const float* __restrict__ src, int rows, int cols, int stride,
                   int rows_pad, u16* __restrict__ hi, u16* __restrict__ lo)
{
  int idx = blockIdx.x * 256 + threadIdx.x;
  int c4cnt = cols >> 2;
  if (idx >= rows_pad * c4cnt) return;
  int row = idx / c4cnt;
  int c4  = (idx % c4cnt) << 2;
  float4 v = make_float4(0.f, 0.f, 0.f, 0.f);
  if (row < rows) v = *(const float4*)(src + (size_t)row * stride + c4);
  float x[4] = {v.x, v.y, v.z, v.w};
  u16 h[4], l[4];
#pragma unroll
  for (int j = 0; j < 4; ++j) {
    h[j] = f2bf(x[j]);
    float hf = __uint_as_float(((unsigned)h[j]) << 16);
    l[j] = f2bf(x[j] - hf);
  }
  size_t off = (size_t)row * cols + c4;
  *(ushort4*)(hi + off) = make_ushort4(h[0], h[1], h[2], h[3]);
  *(ushort4*)(lo + off) = make_ushort4(l[0], l[1], l[2], l[3]);
}

// ---------------------------------------------------------------------------
// Split-bf16 MFMA GEMM: C[M,N] = A[M,K] * B[N,K]^T (+bias).
// A,B given as bf16 hi/lo pairs, row-major [rows][K]. B rows padded to BN mult.
// Wave computes 64x64 (4x4 frags of 16x16x32). Block = WM x WN waves.
// A*B ~= Ah*Bh + Al*Bh + Ah*Bl  (f32 accumulate in AGPRs).
// ---------------------------------------------------------------------------
template<int WM, int WN>
__global__ __launch_bounds__(64 * WM * WN)
void gemm_mfma(const u16* __restrict__ Ah, const u16* __restrict__ Al,
               const u16* __restrict__ Bh, const u16* __restrict__ Bl,
               const float* __restrict__ bias,
               float* __restrict__ C, int ldc, int N, int K)
{
  constexpr int BM = 64 * WM, BN = 64 * WN;
  constexpr int NTHR = 64 * WM * WN;
  __shared__ u16 sA[2][BM][32];
  __shared__ u16 sB[2][BN][32];
  const int tid  = threadIdx.x;
  const int wave = tid >> 6;
  const int lane = tid & 63;
  const int wm   = wave % WM;
  const int wn   = wave / WM;
  const int bm   = blockIdx.x * BM;
  const int bn   = blockIdx.y * BN;
  const int lrow = lane & 15;
  const int lk   = (lane >> 4) * 8;

  f32x4 acc[4][4];
#pragma unroll
  for (int i = 0; i < 4; ++i)
#pragma unroll
    for (int j = 0; j < 4; ++j) acc[i][j] = (f32x4){0.f, 0.f, 0.f, 0.f};

  constexpr int CH_A = BM * 4;          // 16B chunks per hi or lo A tile
  constexpr int CH_B = BN * 4;
  constexpr int CH_TOT = 2 * (CH_A + CH_B);

  for (int k0 = 0; k0 < K; k0 += 32) {
    for (int q = tid; q < CH_TOT; q += NTHR) {
      if (q < 2 * CH_A) {
        int hl = q / CH_A, j = q % CH_A;
        int row = j >> 2, off = (j & 3) * 8;
        const u16* src = (hl ? Al : Ah) + (size_t)(bm + row) * K + k0 + off;
        *(float4*)&sA[hl][row][off] = *(const float4*)src;
      } else {
        int q2 = q - 2 * CH_A;
        int hl = q2 / CH_B, j = q2 % CH_B;
        int row = j >> 2, off = (j & 3) * 8;
        const u16* src = (hl ? Bl : Bh) + (size_t)(bn + row) * K + k0 + off;
        *(float4*)&sB[hl][row][off] = *(const float4*)src;
      }
    }
    __syncthreads();

    bf16x8 a_h[4], a_l[4], b_h[4], b_l[4];
#pragma unroll
    for (int i = 0; i < 4; ++i) {
      a_h[i] = *(const bf16x8*)&sA[0][wm * 64 + i * 16 + lrow][lk];
      a_l[i] = *(const bf16x8*)&sA[1][wm * 64 + i * 16 + lrow][lk];
      b_h[i] = *(const bf16x8*)&sB[0][wn * 64 + i * 16 + lrow][lk];
      b_l[i] = *(const bf16x8*)&sB[1][wn * 64 + i * 16 + lrow][lk];
    }
#pragma unroll
    for (int i = 0; i < 4; ++i)
#pragma unroll
      for (int j = 0; j < 4; ++j) {
        acc[i][j] = __builtin_amdgcn_mfma_f32_16x16x32_bf16(a_h[i], b_h[j], acc[i][j], 0, 0, 0);
        acc[i][j] = __builtin_amdgcn_mfma_f32_16x16x32_bf16(a_l[i], b_h[j], acc[i][j], 0, 0, 0);
        acc[i][j] = __builtin_amdgcn_mfma_f32_16x16x32_bf16(a_h[i], b_l[j], acc[i][j], 0, 0, 0);
      }
    __syncthreads();
  }

  const int r0 = (lane >> 4) * 4;
#pragma unroll
  for (int j = 0; j < 4; ++j) {
    int col = bn + wn * 64 + j * 16 + lrow;
    if (col >= N) continue;
    float bv = bias ? bias[col] : 0.f;
#pragma unroll
    for (int i = 0; i < 4; ++i) {
      int rowb = bm + wm * 64 + i * 16 + r0;
#pragma unroll
      for (int r = 0; r < 4; ++r)
        C[(size_t)(rowb + r) * ldc + col] = acc[i][j][r] + bv;
    }
  }
}

// ---------------------------------------------------------------------------
// dt / lam in EXACT f32 straight from u . W_in rows (bypasses bf16 proj),
// then alpha = exp(dt*A) and u_eff coefficients.
// ---------------------------------------------------------------------------
__global__ __launch_bounds__(256)
void dtlam_kernel(const float* __restrict__ u, const float* __restrict__ W_in,
                  const float* __restrict__ b_in, const float* __restrict__ A_log,
                  float* __restrict__ dtg, float* __restrict__ alphag,
                  float* __restrict__ c0g, float* __restrict__ c1g)
{
  int idx = blockIdx.x * 256 + threadIdx.x;      // L*G = 8192
  if (idx >= L_SEQ * 4) return;
  int l = idx >> 2, g = idx & 3;
  const float4* ur = (const float4*)(u + (size_t)l * 512);
  const float4* wd = (const float4*)(W_in + (size_t)(OFF_DT + g) * 512);
  const float4* wl = (const float4*)(W_in + (size_t)(OFF_DT + 4 + g) * 512);
  float sd = 0.f, sl = 0.f;
  for (int k = 0; k < 128; ++k) {
    float4 a = ur[k], b = wd[k], c = wl[k];
    sd += a.x * b.x + a.y * b.y + a.z * b.z + a.w * b.w;
    sl += a.x * c.x + a.y * c.y + a.z * c.z + a.w * c.w;
  }
  sd += b_in[OFF_DT + g];
  sl += b_in[OFF_DT + 4 + g];
  float dt  = (sd > 20.f) ? sd : log1pf(expf(sd));
  float lam = 1.f / (1.f + expf(-sl));
  float Ag  = -expf(A_log[g]);
  float al  = expf(dt * Ag);
  dtg[idx]    = dt;
  alphag[idx] = al;
  c0g[idx]    = 1.f - lam;
  c1g[idx]    = lam * al;
}

// ---------------------------------------------------------------------------
// f64 inclusive cumsum of dt over L, per group.  grid=4 (g), block=256.
// ---------------------------------------------------------------------------
__global__ __launch_bounds__(256)
void cumsum_dt_kernel(const float* __restrict__ dtg, float* __restrict__ cumdt)
{
  const int g = blockIdx.x;
  const int t = threadIdx.x;
  constexpr int PER = L_SEQ / 256;  // 8
  __shared__ double ps[256];
  float loc[PER];
  double s = 0.0;
  int l0 = t * PER;
  for (int i = 0; i < PER; ++i) {
    loc[i] = dtg[(l0 + i) * 4 + g];
    s += (double)loc[i];
  }
  ps[t] = s;
  __syncthreads();
  for (int off = 1; off < 256; off <<= 1) {
    double v = (t >= off) ? ps[t - off] : 0.0;
    __syncthreads();
    ps[t] += v;
    __syncthreads();
  }
  double c = ps[t] - s;  // exclusive prefix
  for (int i = 0; i < PER; ++i) {
    c += (double)loc[i];
    cumdt[(l0 + i) * 4 + g] = (float)c;
  }
}

// ---------------------------------------------------------------------------
// Per-token: silu(xp) -> xs ; rms+bias+rope for B/C (group level).
// ---------------------------------------------------------------------------
__global__ __launch_bounds__(256)
void pertoken_kernel(const float* __restrict__ proj,
                     const float* __restrict__ cumdt,
                     const float* __restrict__ theta_log,
                     const float* __restrict__ norm_B_w,
                     const float* __restrict__ norm_C_w,
                     const float* __restrict__ bias_B,
                     const float* __restrict__ bias_C,
                     float* __restrict__ xs,
                     float* __restrict__ Brot,
                     float* __restrict__ Crot)
{
  const int l = blockIdx.x;
  const int t = threadIdx.x;
  const size_t prow = (size_t)l * DPROJ;

  for (int i = t; i < 1024; i += 256) {
    float x = proj[prow + OFF_X + i];
    xs[(size_t)l * 1024 + i] = x / (1.f + expf(-x));
  }

  const int g = t >> 6;
  const int e = t & 63;
  float bv = proj[prow + OFF_B + t];
  float cv = proj[prow + OFF_C + t];
  float ssb = bv * bv, ssc = cv * cv;
#pragma unroll
  for (int m = 1; m <= 32; m <<= 1) {
    ssb += __shfl_xor(ssb, m, 64);
    ssc += __shfl_xor(ssc, m, 64);
  }
  float nb = bv * rsqrtf(ssb * (1.f / 64.f) + 1e-5f) * norm_B_w[e] + bias_B[t];
  float nc = cv * rsqrtf(ssc * (1.f / 64.f) + 1e-5f) * norm_C_w[e] + bias_C[t];

  float ang = expf(theta_log[g * 16 + (e >> 2)]) * cumdt[l * 4 + g];
  float ca, sa;
  sincosf(ang, &sa, &ca);   // sincosf writes SIN to 1st ptr, COS to 2nd
  float nb2 = __shfl_xor(nb, 2, 64);
  float nc2 = __shfl_xor(nc, 2, 64);
  bool isre = ((e >> 1) & 1) == 0;
  float Bo, Co;
  if (isre) {
    Bo = nb * ca + nb2 * sa;   // theta = -ang
    Co = nc * ca - nc2 * sa;   // theta = +ang
  } else {
    Bo = nb * ca - nb2 * sa;
    Co = nc * ca + nc2 * sa;
  }
  Brot[(size_t)l * 256 + t] = Bo;
  Crot[(size_t)l * 256 + t] = Co;
}

// ---------------------------------------------------------------------------
// Scan: lane = p, per-thread state H[n=0..31] + uprev[n].
// grid = (NCH, G), block = 256 (4 waves = 4 heads of group g).
// ---------------------------------------------------------------------------
template<bool WITH_Y>
__global__ __launch_bounds__(256)
void scan_chunk(const float* __restrict__ Brot, const float* __restrict__ Crot,
                const float* __restrict__ xup,
                const float* __restrict__ dtg, const float* __restrict__ alphag,
                const float* __restrict__ c0g, const float* __restrict__ c1g,
                const float* __restrict__ hstates_in,
                float* __restrict__ hlast_out, float* __restrict__ y128)
{
  const int c   = blockIdx.x;
  const int g   = blockIdx.y;
  const int wid = threadIdx.x >> 6;
  const int p   = threadIdx.x & 63;
  const int h   = g * 4 + wid;
  const int l0  = c * SCHUNK;

  __shared__ float Bs[SCHUNK][64];
  __shared__ float Cs[SCHUNK][64];
  __shared__ float als[SCHUNK], c0s[SCHUNK], c1s[SCHUNK];

  for (int i = threadIdx.x; i < SCHUNK * 64; i += 256) {
    int l = i >> 6, e = i & 63;
    float dt = dtg[(l0 + l) * 4 + g];
    Bs[l][e] = dt * Brot[(size_t)(l0 + l) * 256 + g * 64 + e];
    if (WITH_Y) Cs[l][e] = Crot[(size_t)(l0 + l) * 256 + g * 64 + e];
  }
  if (threadIdx.x < SCHUNK) {
    int l = threadIdx.x;
    als[l] = alphag[(l0 + l) * 4 + g];
    c0s[l] = c0g[(l0 + l) * 4 + g];
    c1s[l] = c1g[(l0 + l) * 4 + g];
  }
  __syncthreads();

  float H[32], up[32];
  if (WITH_Y) {
    const float* hs = &hstates_in[(((size_t)c * 16 + h) * 64 + p) * 32];
#pragma unroll
    for (int q = 0; q < 8; ++q) {
      float4 v = *reinterpret_cast<const float4*>(hs + 4 * q);
      H[4 * q] = v.x; H[4 * q + 1] = v.y; H[4 * q + 2] = v.z; H[4 * q + 3] = v.w;
    }
  } else {
#pragma unroll
    for (int n = 0; n < 32; ++n) H[n] = 0.f;
  }

  if (c > 0) {
    const int lm = l0 - 1;
    const float dtm = dtg[lm * 4 + g];
    float2 X = *reinterpret_cast<const float2*>(&xup[((size_t)lm * 16 + h) * 128 + 2 * p]);
    float x0 = dtm * X.x, x1 = dtm * X.y;
#pragma unroll
    for (int n = 0; n < 32; ++n) {
      float2 Bv = *reinterpret_cast<const float2*>(&Brot[(size_t)lm * 256 + g * 64 + 2 * n]);
      up[n] = Bv.x * x0 + Bv.y * x1;
    }
  } else {
#pragma unroll
    for (int n = 0; n < 32; ++n) up[n] = 0.f;
  }

  for (int l = 0; l < SCHUNK; ++l) {
    float2 X = *reinterpret_cast<const float2*>(
        &xup[((size_t)(l0 + l) * 16 + h) * 128 + 2 * p]);
    const float al = als[l], cc0 = c0s[l], cc1 = c1s[l];
    float y0 = 0.f, y1 = 0.f;
#pragma unroll
    for (int n2 = 0; n2 < 16; ++n2) {
      float4 Bv = *reinterpret_cast<const float4*>(&Bs[l][4 * n2]);
      float uin0 = Bv.x * X.x + Bv.y * X.y;
      float uin1 = Bv.z * X.x + Bv.w * X.y;
      float ue0 = cc0 * uin0 + cc1 * up[2 * n2];
      float ue1 = cc0 * uin1 + cc1 * up[2 * n2 + 1];
      H[2 * n2]     = al * H[2 * n2]     + ue0;
      H[2 * n2 + 1] = al * H[2 * n2 + 1] + ue1;
      up[2 * n2] = uin0; up[2 * n2 + 1] = uin1;
      if (WITH_Y) {
        float4 Cv = *reinterpret_cast<const float4*>(&Cs[l][4 * n2]);
        y0 = fmaf(H[2 * n2], Cv.x, fmaf(H[2 * n2 + 1], Cv.z, y0));
        y1 = fmaf(H[2 * n2], Cv.y, fmaf(H[2 * n2 + 1], Cv.w, y1));
      }
    }
    if (WITH_Y) {
      *reinterpret_cast<float2*>(&y128[((size_t)(l0 + l) * 16 + h) * 128 + 2 * p]) =
          make_float2(y0, y1);
    }
  }

  if (!WITH_Y) {
    float* hl = &hlast_out[(((size_t)c * 16 + h) * 64 + p) * 32];
#pragma unroll
    for (int q = 0; q < 8; ++q)
      *reinterpret_cast<float4*>(hl + 4 * q) =
          make_float4(H[4 * q], H[4 * q + 1], H[4 * q + 2], H[4 * q + 3]);
  }
}

// ---------------------------------------------------------------------------
// Scan pass B: cross-chunk combine -> h_states (state entering each chunk).
// ---------------------------------------------------------------------------
__global__ __launch_bounds__(256)
void scan_passB(const float* __restrict__ hlast, const float* __restrict__ cumdt,
                const float* __restrict__ A_log, float* __restrict__ hstates)
{
  int idx = blockIdx.x * 256 + threadIdx.x;   // H * P * N = 32768
  int h = idx >> 11;
  int rem = idx & 2047;
  int g = h >> 2;
  float Ag = -expf(A_log[g]);
  float s = 0.f;
  for (int c = 0; c < NCH; ++c) {
    hstates[((size_t)c * 16 + h) * 2048 + rem] = s;
    float sd = cumdt[(c * SCHUNK + SCHUNK - 1) * 4 + g]
             - (c > 0 ? cumdt[(c * SCHUNK - 1) * 4 + g] : 0.f);
    float dec = expf(Ag * sd);
    s = s * dec + hlast[((size_t)c * 16 + h) * 2048 + rem];
  }
}

// ---------------------------------------------------------------------------
// Fuse: yg = (yd + D[h]*xs) * silu(z), in place into proj's z region.
// ---------------------------------------------------------------------------
__global__ __launch_bounds__(256)
void fuse_gate_kernel(const float* __restrict__ yd, const float* __restrict__ xs,
                      const float* __restrict__ Dv, float* __restrict__ proj)
{
  int idx = blockIdx.x * 256 + threadIdx.x;   // L * 1024
  int l = idx >> 10, m = idx & 1023, h = m >> 6;
  float v = yd[((size_t)l * 16 + h) * 64 + (m & 63)] + Dv[h] * xs[idx];
  float z = proj[(size_t)l * DPROJ + m];
  float sz = z / (1.f + expf(-z));
  proj[(size_t)l * DPROJ + m] = v * sz;
}

}  // namespace

extern "C" void kernel_launch(void* const* d_in, const int* in_sizes, int n_in,
                              void* d_out, int out_size, void* d_ws, size_t ws_size,
                              hipStream_t stream)
{
  const float* u         = (const float*)d_in[0];
  const float* W_in      = (const float*)d_in[1];
  const float* b_in      = (const float*)d_in[2];
  const float* W_xup     = (const float*)d_in[3];
  const float* W_ydown   = (const float*)d_in[4];
  const float* A_log     = (const float*)d_in[5];
  const float* theta_log = (const float*)d_in[6];
  const float* Dvec      = (const float*)d_in[7];
  const float* norm_B_w  = (const float*)d_in[8];
  const float* norm_C_w  = (const float*)d_in[9];
  const float* bias_B    = (const float*)d_in[10];
  const float* bias_C    = (const float*)d_in[11];
  const float* W_out     = (const float*)d_in[12];
  float* out = (float*)d_out;

  // ---- f32 workspace carve (floats) ----
  float* proj    = (float*)d_ws;                    // 2048*2568
  float* xs      = proj    + (size_t)L_SEQ * DPROJ; // 2048*1024
  float* dtg     = xs      + (size_t)L_SEQ * 1024;  // 2048*4 each
  float* alphag  = dtg     + L_SEQ * 4;
  float* c0g     = alphag  + L_SEQ * 4;
  float* c1g     = c0g     + L_SEQ * 4;
  float* cumdt   = c1g     + L_SEQ * 4;
  float* Brot    = cumdt   + L_SEQ * 4;             // 2048*256
  float* Crot    = Brot    + (size_t)L_SEQ * 256;
  float* xup     = Crot    + (size_t)L_SEQ * 256;   // 32768*128 (region B)
  float* y128    = xup     + (size_t)32768 * 128;   // 32768*128
  float* yd      = y128    + (size_t)32768 * 128;   // 32768*64
  float* hlast   = y128;                            // alias (dead before y-writes)
  float* hstates = yd;                              // alias (dead before gemm9)

  // ---- bf16 hi/lo region A (u16), phase-overlaid ----
  u16* rA = (u16*)(yd + (size_t)32768 * 64);
  // phase 1: proj gemm operands
  u16* u_hi   = rA;
  u16* u_lo   = u_hi + (size_t)2048 * 512;
  u16* win_hi = u_lo + (size_t)2048 * 512;          // padded to 2688 rows
  u16* win_lo = win_hi + (size_t)2688 * 512;
  // phase 2: xup gemm operands (after gemm1 done)
  u16* xs_hi   = rA;
  u16* xs_lo   = xs_hi + (size_t)32768 * 64;
  u16* wxup_hi = xs_lo + (size_t)32768 * 64;
  u16* wxup_lo = wxup_hi + (size_t)128 * 64;
  // phase 3: ydown operands (y128 bf16 goes to region B = xup, dead after scans)
  u16* wyd_hi  = rA;
  u16* wyd_lo  = wyd_hi + (size_t)64 * 128;
  u16* y128_hi = (u16*)xup;
  u16* y128_lo = y128_hi + (size_t)32768 * 128;
  // phase 4: out gemm operands (after gemm ydown done)
  u16* yg_hi   = rA;
  u16* yg_lo   = yg_hi + (size_t)2048 * 1024;
  u16* wout_hi = yg_lo + (size_t)2048 * 1024;
  u16* wout_lo = wout_hi + (size_t)512 * 1024;

  // 1. convert u, W_in -> split bf16 ; proj = u @ W_in^T + b_in (MFMA)
  convert_split<<<dim3(1024), 256, 0, stream>>>(u, 2048, 512, 512, 2048, u_hi, u_lo);
  convert_split<<<dim3(1344), 256, 0, stream>>>(W_in, 2568, 512, 512, 2688, win_hi, win_lo);
  gemm_mfma<1, 2><<<dim3(32, 21), 128, 0, stream>>>(
      u_hi, u_lo, win_hi, win_lo, b_in, proj, DPROJ, DPROJ, 512);

  // 2. dt/lam exact-f32 from u . W_in rows; 3. f64 cumsum
  dtlam_kernel<<<dim3(32), 256, 0, stream>>>(u, W_in, b_in, A_log, dtg, alphag, c0g, c1g);
  cumsum_dt_kernel<<<dim3(4), 256, 0, stream>>>(dtg, cumdt);

  // 4. per-token: silu(xp), rms+bias+rope -> Brot/Crot
  pertoken_kernel<<<dim3(L_SEQ), 256, 0, stream>>>(
      proj, cumdt, theta_log, norm_B_w, norm_C_w, bias_B, bias_C, xs, Brot, Crot);

  // 5. x_up = xs @ W_xup^T (MFMA)
  convert_split<<<dim3(2048), 256, 0, stream>>>(xs, 32768, 64, 64, 32768, xs_hi, xs_lo);
  convert_split<<<dim3(8), 256, 0, stream>>>(W_xup, 128, 64, 64, 128, wxup_hi, wxup_lo);
  gemm_mfma<2, 2><<<dim3(256, 1), 256, 0, stream>>>(
      xs_hi, xs_lo, wxup_hi, wxup_lo, nullptr, xup, 128, 128, 64);

  // 6-8. chunked scan (state-in-registers)
  scan_chunk<false><<<dim3(NCH, 4), 256, 0, stream>>>(
      Brot, Crot, xup, dtg, alphag, c0g, c1g, nullptr, hlast, nullptr);
  scan_passB<<<dim3(128), 256, 0, stream>>>(hlast, cumdt, A_log, hstates);
  scan_chunk<true><<<dim3(NCH, 4), 256, 0, stream>>>(
      Brot, Crot, xup, dtg, alphag, c0g, c1g, hstates, nullptr, y128);

  // 9. yd = y128 @ W_ydown^T (MFMA); y128 bf16 into dead xup region
  convert_split<<<dim3(4096), 256, 0, stream>>>(y128, 32768, 128, 128, 32768, y128_hi, y128_lo);
  convert_split<<<dim3(8), 256, 0, stream>>>(W_ydown, 64, 128, 128, 64, wyd_hi, wyd_lo);
  gemm_mfma<2, 1><<<dim3(256, 1), 128, 0, stream>>>(
      y128_hi, y128_lo, wyd_hi, wyd_lo, nullptr, yd, 64, 64, 128);

  // 10. gate: yg = (yd + D*xs) * silu(z), in place into proj[:, 0:1024]
  fuse_gate_kernel<<<dim3(8192), 256, 0, stream>>>(yd, xs, Dvec, proj);

  // 11. out = yg @ W_out^T (MFMA)
  convert_split<<<dim3(2048), 256, 0, stream>>>(proj, 2048, 1024, DPROJ, 2048, yg_hi, yg_lo);
  convert_split<<<dim3(512), 256, 0, stream>>>(W_out, 512, 1024, 1024, 512, wout_hi, wout_lo);
  gemm_mfma<1, 1><<<dim3(32, 8), 64, 0, stream>>>(
      yg_hi, yg_lo, wout_hi, wout_lo, nullptr, out, 512, 512, 1024);
}

// Round 6
// 351.084 us; speedup vs baseline: 1.1876x; 1.1876x over previous
//
#include <hip/hip_runtime.h>
#include <hip/hip_bf16.h>
#include <math.h>

namespace {

typedef unsigned short u16;
typedef __bf16 bf16x8 __attribute__((ext_vector_type(8)));
typedef float f32x4 __attribute__((ext_vector_type(4)));

constexpr int L_SEQ  = 2048;
constexpr int DPROJ  = 2568;
constexpr int OFF_X  = 1024;
constexpr int OFF_B  = 2048;
constexpr int OFF_C  = 2304;
constexpr int OFF_DT = 2560;
constexpr int SCHUNK = 32;
constexpr int NCH    = L_SEQ / SCHUNK;  // 64
constexpr int LDSK   = 40;              // padded inner dim (u16): 80B row stride
                                        // -> 20-bank stride -> 2-way alias = free

// ---------------------------------------------------------------------------
// f32 -> (bf16 hi, bf16 lo) split conversion. Pads rows to rows_pad w/ zeros.
// ---------------------------------------------------------------------------
__device__ inline u16 f2bf(float x) {
  unsigned u = __float_as_uint(x);
  unsigned r = u + 0x7FFFu + ((u >> 16) & 1u);
  return (u16)(r >> 16);
}

__global__ __launch_bounds__(256)
void convert_split(const float* __restrict__ src, int rows, int cols, int stride,
                   int rows_pad, u16* __restrict__ hi, u16* __restrict__ lo)
{
  int idx = blockIdx.x * 256 + threadIdx.x;
  int c4cnt = cols >> 2;
  if (idx >= rows_pad * c4cnt) return;
  int row = idx / c4cnt;
  int c4  = (idx % c4cnt) << 2;
  float4 v = make_float4(0.f, 0.f, 0.f, 0.f);
  if (row < rows) v = *(const float4*)(src + (size_t)row * stride + c4);
  float x[4] = {v.x, v.y, v.z, v.w};
  u16 h[4], l[4];
#pragma unroll
  for (int j = 0; j < 4; ++j) {
    h[j] = f2bf(x[j]);
    float hf = __uint_as_float(((unsigned)h[j]) << 16);
    l[j] = f2bf(x[j] - hf);
  }
  size_t off = (size_t)row * cols + c4;
  *(ushort4*)(hi + off) = make_ushort4(h[0], h[1], h[2], h[3]);
  *(ushort4*)(lo + off) = make_ushort4(l[0], l[1], l[2], l[3]);
}

// ---------------------------------------------------------------------------
// Split-bf16 MFMA GEMM: C[M,N] = A[M,K] * B[N,K]^T (+bias).
// Wave computes 64x64 (4x4 frags of 16x16x32). Block = WMW x WNW waves
// (always 4 waves / 256 threads). A*B ~= Ah*Bh + Al*Bh + Ah*Bl.
// LDS rows padded to LDSK u16 to kill the 8-way read bank conflict.
// ---------------------------------------------------------------------------
template<int WMW, int WNW>
__global__ __launch_bounds__(64 * WMW * WNW)
void gemm_mfma(const u16* __restrict__ Ah, const u16* __restrict__ Al,
               const u16* __restrict__ Bh, const u16* __restrict__ Bl,
               const float* __restrict__ bias,
               float* __restrict__ C, int ldc, int N, int K)
{
  constexpr int BM = 64 * WMW, BN = 64 * WNW;
  constexpr int NTHR = 64 * WMW * WNW;
  __shared__ u16 sA[2][BM][LDSK];
  __shared__ u16 sB[2][BN][LDSK];
  const int tid  = threadIdx.x;
  const int wave = tid >> 6;
  const int lane = tid & 63;
  const int wm   = wave % WMW;
  const int wn   = wave / WMW;
  const int bm   = blockIdx.x * BM;
  const int bn   = blockIdx.y * BN;
  const int lrow = lane & 15;
  const int lk   = (lane >> 4) * 8;

  f32x4 acc[4][4];
#pragma unroll
  for (int i = 0; i < 4; ++i)
#pragma unroll
    for (int j = 0; j < 4; ++j) acc[i][j] = (f32x4){0.f, 0.f, 0.f, 0.f};

  constexpr int CH_A = BM * 4;          // 16B chunks per hi or lo A tile
  constexpr int CH_B = BN * 4;
  constexpr int CH_TOT = 2 * (CH_A + CH_B);

  for (int k0 = 0; k0 < K; k0 += 32) {
    for (int q = tid; q < CH_TOT; q += NTHR) {
      if (q < 2 * CH_A) {
        int hl = q / CH_A, j = q % CH_A;
        int row = j >> 2, off = (j & 3) * 8;
        const u16* src = (hl ? Al : Ah) + (size_t)(bm + row) * K + k0 + off;
        *(float4*)&sA[hl][row][off] = *(const float4*)src;
      } else {
        int q2 = q - 2 * CH_A;
        int hl = q2 / CH_B, j = q2 % CH_B;
        int row = j >> 2, off = (j & 3) * 8;
        const u16* src = (hl ? Bl : Bh) + (size_t)(bn + row) * K + k0 + off;
        *(float4*)&sB[hl][row][off] = *(const float4*)src;
      }
    }
    __syncthreads();

    bf16x8 a_h[4], a_l[4], b_h[4], b_l[4];
#pragma unroll
    for (int i = 0; i < 4; ++i) {
      a_h[i] = *(const bf16x8*)&sA[0][wm * 64 + i * 16 + lrow][lk];
      a_l[i] = *(const bf16x8*)&sA[1][wm * 64 + i * 16 + lrow][lk];
      b_h[i] = *(const bf16x8*)&sB[0][wn * 64 + i * 16 + lrow][lk];
      b_l[i] = *(const bf16x8*)&sB[1][wn * 64 + i * 16 + lrow][lk];
    }
#pragma unroll
    for (int i = 0; i < 4; ++i)
#pragma unroll
      for (int j = 0; j < 4; ++j) {
        acc[i][j] = __builtin_amdgcn_mfma_f32_16x16x32_bf16(a_h[i], b_h[j], acc[i][j], 0, 0, 0);
        acc[i][j] = __builtin_amdgcn_mfma_f32_16x16x32_bf16(a_l[i], b_h[j], acc[i][j], 0, 0, 0);
        acc[i][j] = __builtin_amdgcn_mfma_f32_16x16x32_bf16(a_h[i], b_l[j], acc[i][j], 0, 0, 0);
      }
    __syncthreads();
  }

  const int r0 = (lane >> 4) * 4;
#pragma unroll
  for (int j = 0; j < 4; ++j) {
    int col = bn + wn * 64 + j * 16 + lrow;
    if (col >= N) continue;
    float bv = bias ? bias[col] : 0.f;
#pragma unroll
    for (int i = 0; i < 4; ++i) {
      int rowb = bm + wm * 64 + i * 16 + r0;
#pragma unroll
      for (int r = 0; r < 4; ++r)
        C[(size_t)(rowb + r) * ldc + col] = acc[i][j][r] + bv;
    }
  }
}

// ---------------------------------------------------------------------------
// dt / lam in EXACT f32 straight from u . W_in rows (bypasses bf16 proj),
// then alpha = exp(dt*A) and u_eff coefficients.
// ---------------------------------------------------------------------------
__global__ __launch_bounds__(256)
void dtlam_kernel(const float* __restrict__ u, const float* __restrict__ W_in,
                  const float* __restrict__ b_in, const float* __restrict__ A_log,
                  float* __restrict__ dtg, float* __restrict__ alphag,
                  float* __restrict__ c0g, float* __restrict__ c1g)
{
  int idx = blockIdx.x * 256 + threadIdx.x;      // L*G = 8192
  if (idx >= L_SEQ * 4) return;
  int l = idx >> 2, g = idx & 3;
  const float4* ur = (const float4*)(u + (size_t)l * 512);
  const float4* wd = (const float4*)(W_in + (size_t)(OFF_DT + g) * 512);
  const float4* wl = (const float4*)(W_in + (size_t)(OFF_DT + 4 + g) * 512);
  float sd = 0.f, sl = 0.f;
  for (int k = 0; k < 128; ++k) {
    float4 a = ur[k], b = wd[k], c = wl[k];
    sd += a.x * b.x + a.y * b.y + a.z * b.z + a.w * b.w;
    sl += a.x * c.x + a.y * c.y + a.z * c.z + a.w * c.w;
  }
  sd += b_in[OFF_DT + g];
  sl += b_in[OFF_DT + 4 + g];
  float dt  = (sd > 20.f) ? sd : log1pf(expf(sd));
  float lam = 1.f / (1.f + expf(-sl));
  float Ag  = -expf(A_log[g]);
  float al  = expf(dt * Ag);
  dtg[idx]    = dt;
  alphag[idx] = al;
  c0g[idx]    = 1.f - lam;
  c1g[idx]    = lam * al;
}

// ---------------------------------------------------------------------------
// f64 inclusive cumsum of dt over L, per group.  grid=4 (g), block=256.
// ---------------------------------------------------------------------------
__global__ __launch_bounds__(256)
void cumsum_dt_kernel(const float* __restrict__ dtg, float* __restrict__ cumdt)
{
  const int g = blockIdx.x;
  const int t = threadIdx.x;
  constexpr int PER = L_SEQ / 256;  // 8
  __shared__ double ps[256];
  float loc[PER];
  double s = 0.0;
  int l0 = t * PER;
  for (int i = 0; i < PER; ++i) {
    loc[i] = dtg[(l0 + i) * 4 + g];
    s += (double)loc[i];
  }
  ps[t] = s;
  __syncthreads();
  for (int off = 1; off < 256; off <<= 1) {
    double v = (t >= off) ? ps[t - off] : 0.0;
    __syncthreads();
    ps[t] += v;
    __syncthreads();
  }
  double c = ps[t] - s;  // exclusive prefix
  for (int i = 0; i < PER; ++i) {
    c += (double)loc[i];
    cumdt[(l0 + i) * 4 + g] = (float)c;
  }
}

// ---------------------------------------------------------------------------
// Per-token: silu(xp) -> xs ; rms+bias+rope for B/C (group level).
// ---------------------------------------------------------------------------
__global__ __launch_bounds__(256)
void pertoken_kernel(const float* __restrict__ proj,
                     const float* __restrict__ cumdt,
                     const float* __restrict__ theta_log,
                     const float* __restrict__ norm_B_w,
                     const float* __restrict__ norm_C_w,
                     const float* __restrict__ bias_B,
                     const float* __restrict__ bias_C,
                     float* __restrict__ xs,
                     float* __restrict__ Brot,
                     float* __restrict__ Crot)
{
  const int l = blockIdx.x;
  const int t = threadIdx.x;
  const size_t prow = (size_t)l * DPROJ;

  for (int i = t; i < 1024; i += 256) {
    float x = proj[prow + OFF_X + i];
    xs[(size_t)l * 1024 + i] = x / (1.f + expf(-x));
  }

  const int g = t >> 6;
  const int e = t & 63;
  float bv = proj[prow + OFF_B + t];
  float cv = proj[prow + OFF_C + t];
  float ssb = bv * bv, ssc = cv * cv;
#pragma unroll
  for (int m = 1; m <= 32; m <<= 1) {
    ssb += __shfl_xor(ssb, m, 64);
    ssc += __shfl_xor(ssc, m, 64);
  }
  float nb = bv * rsqrtf(ssb * (1.f / 64.f) + 1e-5f) * norm_B_w[e] + bias_B[t];
  float nc = cv * rsqrtf(ssc * (1.f / 64.f) + 1e-5f) * norm_C_w[e] + bias_C[t];

  float ang = expf(theta_log[g * 16 + (e >> 2)]) * cumdt[l * 4 + g];
  float ca, sa;
  sincosf(ang, &sa, &ca);   // sincosf writes SIN to 1st ptr, COS to 2nd
  float nb2 = __shfl_xor(nb, 2, 64);
  float nc2 = __shfl_xor(nc, 2, 64);
  bool isre = ((e >> 1) & 1) == 0;
  float Bo, Co;
  if (isre) {
    Bo = nb * ca + nb2 * sa;   // theta = -ang
    Co = nc * ca - nc2 * sa;   // theta = +ang
  } else {
    Bo = nb * ca - nb2 * sa;
    Co = nc * ca + nc2 * sa;
  }
  Brot[(size_t)l * 256 + t] = Bo;
  Crot[(size_t)l * 256 + t] = Co;
}

// ---------------------------------------------------------------------------
// Scan: lane = p, per-thread state H[n=0..31] + uprev[n].
// grid = (NCH, G), block = 256 (4 waves = 4 heads of group g).
// ---------------------------------------------------------------------------
template<bool WITH_Y>
__global__ __launch_bounds__(256)
void scan_chunk(const float* __restrict__ Brot, const float* __restrict__ Crot,
                const float* __restrict__ xup,
                const float* __restrict__ dtg, const float* __restrict__ alphag,
                const float* __restrict__ c0g, const float* __restrict__ c1g,
                const float* __restrict__ hstates_in,
                float* __restrict__ hlast_out, float* __restrict__ y128)
{
  const int c   = blockIdx.x;
  const int g   = blockIdx.y;
  const int wid = threadIdx.x >> 6;
  const int p   = threadIdx.x & 63;
  const int h   = g * 4 + wid;
  const int l0  = c * SCHUNK;

  __shared__ float Bs[SCHUNK][64];
  __shared__ float Cs[SCHUNK][64];
  __shared__ float als[SCHUNK], c0s[SCHUNK], c1s[SCHUNK];

  for (int i = threadIdx.x; i < SCHUNK * 64; i += 256) {
    int l = i >> 6, e = i & 63;
    float dt = dtg[(l0 + l) * 4 + g];
    Bs[l][e] = dt * Brot[(size_t)(l0 + l) * 256 + g * 64 + e];
    if (WITH_Y) Cs[l][e] = Crot[(size_t)(l0 + l) * 256 + g * 64 + e];
  }
  if (threadIdx.x < SCHUNK) {
    int l = threadIdx.x;
    als[l] = alphag[(l0 + l) * 4 + g];
    c0s[l] = c0g[(l0 + l) * 4 + g];
    c1s[l] = c1g[(l0 + l) * 4 + g];
  }
  __syncthreads();

  float H[32], up[32];
  if (WITH_Y) {
    const float* hs = &hstates_in[(((size_t)c * 16 + h) * 64 + p) * 32];
#pragma unroll
    for (int q = 0; q < 8; ++q) {
      float4 v = *reinterpret_cast<const float4*>(hs + 4 * q);
      H[4 * q] = v.x; H[4 * q + 1] = v.y; H[4 * q + 2] = v.z; H[4 * q + 3] = v.w;
    }
  } else {
#pragma unroll
    for (int n = 0; n < 32; ++n) H[n] = 0.f;
  }

  if (c > 0) {
    const int lm = l0 - 1;
    const float dtm = dtg[lm * 4 + g];
    float2 X = *reinterpret_cast<const float2*>(&xup[((size_t)lm * 16 + h) * 128 + 2 * p]);
    float x0 = dtm * X.x, x1 = dtm * X.y;
#pragma unroll
    for (int n = 0; n < 32; ++n) {
      float2 Bv = *reinterpret_cast<const float2*>(&Brot[(size_t)lm * 256 + g * 64 + 2 * n]);
      up[n] = Bv.x * x0 + Bv.y * x1;
    }
  } else {
#pragma unroll
    for (int n = 0; n < 32; ++n) up[n] = 0.f;
  }

  for (int l = 0; l < SCHUNK; ++l) {
    float2 X = *reinterpret_cast<const float2*>(
        &xup[((size_t)(l0 + l) * 16 + h) * 128 + 2 * p]);
    const float al = als[l], cc0 = c0s[l], cc1 = c1s[l];
    float y0 = 0.f, y1 = 0.f;
#pragma unroll
    for (int n2 = 0; n2 < 16; ++n2) {
      float4 Bv = *reinterpret_cast<const float4*>(&Bs[l][4 * n2]);
      float uin0 = Bv.x * X.x + Bv.y * X.y;
      float uin1 = Bv.z * X.x + Bv.w * X.y;
      float ue0 = cc0 * uin0 + cc1 * up[2 * n2];
      float ue1 = cc0 * uin1 + cc1 * up[2 * n2 + 1];
      H[2 * n2]     = al * H[2 * n2]     + ue0;
      H[2 * n2 + 1] = al * H[2 * n2 + 1] + ue1;
      up[2 * n2] = uin0; up[2 * n2 + 1] = uin1;
      if (WITH_Y) {
        float4 Cv = *reinterpret_cast<const float4*>(&Cs[l][4 * n2]);
        y0 = fmaf(H[2 * n2], Cv.x, fmaf(H[2 * n2 + 1], Cv.z, y0));
        y1 = fmaf(H[2 * n2], Cv.y, fmaf(H[2 * n2 + 1], Cv.w, y1));
      }
    }
    if (WITH_Y) {
      *reinterpret_cast<float2*>(&y128[((size_t)(l0 + l) * 16 + h) * 128 + 2 * p]) =
          make_float2(y0, y1);
    }
  }

  if (!WITH_Y) {
    float* hl = &hlast_out[(((size_t)c * 16 + h) * 64 + p) * 32];
#pragma unroll
    for (int q = 0; q < 8; ++q)
      *reinterpret_cast<float4*>(hl + 4 * q) =
          make_float4(H[4 * q], H[4 * q + 1], H[4 * q + 2], H[4 * q + 3]);
  }
}

// ---------------------------------------------------------------------------
// Scan pass B: cross-chunk combine -> h_states (state entering each chunk).
// ---------------------------------------------------------------------------
__global__ __launch_bounds__(256)
void scan_passB(const float* __restrict__ hlast, const float* __restrict__ cumdt,
                const float* __restrict__ A_log, float* __restrict__ hstates)
{
  int idx = blockIdx.x * 256 + threadIdx.x;   // H * P * N = 32768
  int h = idx >> 11;
  int rem = idx & 2047;
  int g = h >> 2;
  float Ag = -expf(A_log[g]);
  float s = 0.f;
  for (int c = 0; c < NCH; ++c) {
    hstates[((size_t)c * 16 + h) * 2048 + rem] = s;
    float sd = cumdt[(c * SCHUNK + SCHUNK - 1) * 4 + g]
             - (c > 0 ? cumdt[(c * SCHUNK - 1) * 4 + g] : 0.f);
    float dec = expf(Ag * sd);
    s = s * dec + hlast[((size_t)c * 16 + h) * 2048 + rem];
  }
}

// ---------------------------------------------------------------------------
// Fuse: yg = (yd + D[h]*xs) * silu(z), in place into proj's z region.
// ---------------------------------------------------------------------------
__global__ __launch_bounds__(256)
void fuse_gate_kernel(const float* __restrict__ yd, const float* __restrict__ xs,
                      const float* __restrict__ Dv, float* __restrict__ proj)
{
  int idx = blockIdx.x * 256 + threadIdx.x;   // L * 1024
  int l = idx >> 10, m = idx & 1023, h = m >> 6;
  float v = yd[((size_t)l * 16 + h) * 64 + (m & 63)] + Dv[h] * xs[idx];
  float z = proj[(size_t)l * DPROJ + m];
  float sz = z / (1.f + expf(-z));
  proj[(size_t)l * DPROJ + m] = v * sz;
}

}  // namespace

extern "C" void kernel_launch(void* const* d_in, const int* in_sizes, int n_in,
                              void* d_out, int out_size, void* d_ws, size_t ws_size,
                              hipStream_t stream)
{
  const float* u         = (const float*)d_in[0];
  const float* W_in      = (const float*)d_in[1];
  const float* b_in      = (const float*)d_in[2];
  const float* W_xup     = (const float*)d_in[3];
  const float* W_ydown   = (const float*)d_in[4];
  const float* A_log     = (const float*)d_in[5];
  const float* theta_log = (const float*)d_in[6];
  const float* Dvec      = (const float*)d_in[7];
  const float* norm_B_w  = (const float*)d_in[8];
  const float* norm_C_w  = (const float*)d_in[9];
  const float* bias_B    = (const float*)d_in[10];
  const float* bias_C    = (const float*)d_in[11];
  const float* W_out     = (const float*)d_in[12];
  float* out = (float*)d_out;

  // ---- f32 workspace carve (floats) ----
  float* proj    = (float*)d_ws;                    // 2048*2568
  float* xs      = proj    + (size_t)L_SEQ * DPROJ; // 2048*1024
  float* dtg     = xs      + (size_t)L_SEQ * 1024;  // 2048*4 each
  float* alphag  = dtg     + L_SEQ * 4;
  float* c0g     = alphag  + L_SEQ * 4;
  float* c1g     = c0g     + L_SEQ * 4;
  float* cumdt   = c1g     + L_SEQ * 4;
  float* Brot    = cumdt   + L_SEQ * 4;             // 2048*256
  float* Crot    = Brot    + (size_t)L_SEQ * 256;
  float* xup     = Crot    + (size_t)L_SEQ * 256;   // 32768*128 (region B)
  float* y128    = xup     + (size_t)32768 * 128;   // 32768*128
  float* yd      = y128    + (size_t)32768 * 128;   // 32768*64
  float* hlast   = y128;                            // alias (dead before y-writes)
  float* hstates = yd;                              // alias (dead before gemm9)

  // ---- bf16 hi/lo region A (u16), phase-overlaid ----
  u16* rA = (u16*)(yd + (size_t)32768 * 64);
  // phase 1: proj gemm operands
  u16* u_hi   = rA;
  u16* u_lo   = u_hi + (size_t)2048 * 512;
  u16* win_hi = u_lo + (size_t)2048 * 512;          // padded to 2688 rows
  u16* win_lo = win_hi + (size_t)2688 * 512;
  // phase 2: xup gemm operands (after gemm1 done)
  u16* xs_hi   = rA;
  u16* xs_lo   = xs_hi + (size_t)32768 * 64;
  u16* wxup_hi = xs_lo + (size_t)32768 * 64;
  u16* wxup_lo = wxup_hi + (size_t)128 * 64;
  // phase 3: ydown operands (y128 bf16 goes to region B = xup, dead after scans)
  u16* wyd_hi  = rA;
  u16* wyd_lo  = wyd_hi + (size_t)64 * 128;
  u16* y128_hi = (u16*)xup;
  u16* y128_lo = y128_hi + (size_t)32768 * 128;
  // phase 4: out gemm operands (after gemm ydown done)
  u16* yg_hi   = rA;
  u16* yg_lo   = yg_hi + (size_t)2048 * 1024;
  u16* wout_hi = yg_lo + (size_t)2048 * 1024;
  u16* wout_lo = wout_hi + (size_t)512 * 1024;

  // 1. convert u, W_in -> split bf16 ; proj = u @ W_in^T + b_in (MFMA)
  convert_split<<<dim3(1024), 256, 0, stream>>>(u, 2048, 512, 512, 2048, u_hi, u_lo);
  convert_split<<<dim3(1344), 256, 0, stream>>>(W_in, 2568, 512, 512, 2688, win_hi, win_lo);
  gemm_mfma<2, 2><<<dim3(16, 21), 256, 0, stream>>>(
      u_hi, u_lo, win_hi, win_lo, b_in, proj, DPROJ, DPROJ, 512);

  // 2. dt/lam exact-f32 from u . W_in rows; 3. f64 cumsum
  dtlam_kernel<<<dim3(32), 256, 0, stream>>>(u, W_in, b_in, A_log, dtg, alphag, c0g, c1g);
  cumsum_dt_kernel<<<dim3(4), 256, 0, stream>>>(dtg, cumdt);

  // 4. per-token: silu(xp), rms+bias+rope -> Brot/Crot
  pertoken_kernel<<<dim3(L_SEQ), 256, 0, stream>>>(
      proj, cumdt, theta_log, norm_B_w, norm_C_w, bias_B, bias_C, xs, Brot, Crot);

  // 5. x_up = xs @ W_xup^T (MFMA)
  convert_split<<<dim3(2048), 256, 0, stream>>>(xs, 32768, 64, 64, 32768, xs_hi, xs_lo);
  convert_split<<<dim3(8), 256, 0, stream>>>(W_xup, 128, 64, 64, 128, wxup_hi, wxup_lo);
  gemm_mfma<2, 2><<<dim3(256, 1), 256, 0, stream>>>(
      xs_hi, xs_lo, wxup_hi, wxup_lo, nullptr, xup, 128, 128, 64);

  // 6-8. chunked scan (state-in-registers)
  scan_chunk<false><<<dim3(NCH, 4), 256, 0, stream>>>(
      Brot, Crot, xup, dtg, alphag, c0g, c1g, nullptr, hlast, nullptr);
  scan_passB<<<dim3(128), 256, 0, stream>>>(hlast, cumdt, A_log, hstates);
  scan_chunk<true><<<dim3(NCH, 4), 256, 0, stream>>>(
      Brot, Crot, xup, dtg, alphag, c0g, c1g, hstates, nullptr, y128);

  // 9. yd = y128 @ W_ydown^T (MFMA); y128 bf16 into dead xup region
  convert_split<<<dim3(4096), 256, 0, stream>>>(y128, 32768, 128, 128, 32768, y128_hi, y128_lo);
  convert_split<<<dim3(8), 256, 0, stream>>>(W_ydown, 64, 128, 128, 64, wyd_hi, wyd_lo);
  gemm_mfma<4, 1><<<dim3(128, 1), 256, 0, stream>>>(
      y128_hi, y128_lo, wyd_hi, wyd_lo, nullptr, yd, 64, 64, 128);

  // 10. gate: yg = (yd + D*xs) * silu(z), in place into proj[:, 0:1024]
  fuse_gate_kernel<<<dim3(8192), 256, 0, stream>>>(yd, xs, Dvec, proj);

  // 11. out = yg @ W_out^T (MFMA)
  convert_split<<<dim3(2048), 256, 0, stream>>>(proj, 2048, 1024, DPROJ, 2048, yg_hi, yg_lo);
  convert_split<<<dim3(512), 256, 0, stream>>>(W_out, 512, 1024, 1024, 512, wout_hi, wout_lo);
  gemm_mfma<2, 2><<<dim3(16, 4), 256, 0, stream>>>(
      yg_hi, yg_lo, wout_hi, wout_lo, nullptr, out, 512, 512, 1024);
}

// Round 7
// 305.231 us; speedup vs baseline: 1.3660x; 1.1502x over previous
//
#include <hip/hip_runtime.h>
#include <hip/hip_bf16.h>
#include <math.h>

namespace {

typedef unsigned short u16;
typedef __bf16 bf16x8 __attribute__((ext_vector_type(8)));
typedef float f32x4 __attribute__((ext_vector_type(4)));

constexpr int L_SEQ  = 2048;
constexpr int DPROJ  = 2568;
constexpr int OFF_X  = 1024;
constexpr int OFF_B  = 2048;
constexpr int OFF_C  = 2304;
constexpr int OFF_DT = 2560;
constexpr int SCHUNK = 32;
constexpr int NCH    = L_SEQ / SCHUNK;  // 64

// ---------------------------------------------------------------------------
// f32 -> (bf16 hi, bf16 lo) split conversion. Pads rows to rows_pad w/ zeros.
// ---------------------------------------------------------------------------
__device__ inline u16 f2bf(float x) {
  unsigned u = __float_as_uint(x);
  unsigned r = u + 0x7FFFu + ((u >> 16) & 1u);
  return (u16)(r >> 16);
}

__global__ __launch_bounds__(256)
void convert_split(const float* __restrict__ src, int rows, int cols, int stride,
                   int rows_pad, u16* __restrict__ hi, u16* __restrict__ lo)
{
  int idx = blockIdx.x * 256 + threadIdx.x;
  int c4cnt = cols >> 2;
  if (idx >= rows_pad * c4cnt) return;
  int row = idx / c4cnt;
  int c4  = (idx % c4cnt) << 2;
  float4 v = make_float4(0.f, 0.f, 0.f, 0.f);
  if (row < rows) v = *(const float4*)(src + (size_t)row * stride + c4);
  float x[4] = {v.x, v.y, v.z, v.w};
  u16 h[4], l[4];
#pragma unroll
  for (int j = 0; j < 4; ++j) {
    h[j] = f2bf(x[j]);
    float hf = __uint_as_float(((unsigned)h[j]) << 16);
    l[j] = f2bf(x[j] - hf);
  }
  size_t off = (size_t)row * cols + c4;
  *(ushort4*)(hi + off) = make_ushort4(h[0], h[1], h[2], h[3]);
  *(ushort4*)(lo + off) = make_ushort4(l[0], l[1], l[2], l[3]);
}

// ---------------------------------------------------------------------------
// Split-bf16 MFMA GEMM: C[M,N] = A[M,K] * B[N,K]^T (+bias).
// Wave computes 64x64 (4x4 frags of 16x16x32). A*B ~= Ah*Bh + Al*Bh + Ah*Bl.
// LDS in FRAGMENT ORDER: subtile (hl, rowgrp i, kc) is a contiguous 1KB block,
// element (r) at ((hl*(BM/16)+i)*4+kc)*128 + r*8 (u16 units). A wave's
// ds_read_b128 then spans a contiguous 1KB -> conflict-free; staging writes
// are a permutation of a contiguous span -> conflict-free.
// Register-prefetch double buffering hides global latency under MFMA.
// Optional split-K via blockIdx.z: slice z covers K window [z*Klen, (z+1)*Klen),
// writing to C + z*c_slice.
// ---------------------------------------------------------------------------
template<int WMW, int WNW, int NTHR>
__global__ __launch_bounds__(NTHR)
void gemm_mfma(const u16* __restrict__ Ah, const u16* __restrict__ Al,
               const u16* __restrict__ Bh, const u16* __restrict__ Bl,
               const float* __restrict__ bias,
               float* __restrict__ C, int ldc, int N,
               int Kstride, int Klen, size_t c_slice)
{
  constexpr int BM = 64 * WMW, BN = 64 * WNW;
  static_assert(NTHR == 64 * WMW * WNW, "1 wave per 64x64 tile");
  constexpr int CH_A = BM * 4;               // 16B chunks per hi-or-lo A tile
  constexpr int CH_B = BN * 4;
  constexpr int CH_TOT = 2 * (CH_A + CH_B);
  constexpr int PER = CH_TOT / NTHR;
  static_assert(CH_TOT % NTHR == 0, "chunks must divide threads");

  __shared__ u16 sAB[2 * BM * 32 + 2 * BN * 32];

  const int tid  = threadIdx.x;
  const int wave = tid >> 6;
  const int lane = tid & 63;
  const int wm   = wave % WMW;
  const int wn   = wave / WMW;
  const int bm   = blockIdx.x * BM;
  const int bn   = blockIdx.y * BN;
  const int koff = blockIdx.z * Klen;
  const int lrow = lane & 15;
  const int lkc  = lane >> 4;

  // Per-thread staging chunk descriptors (compile-time count PER).
  const u16* gsrc[PER];
  int        loff[PER];
#pragma unroll
  for (int t = 0; t < PER; ++t) {
    int q = tid + t * NTHR;
    if (q < 2 * CH_A) {
      int hl = q / CH_A, j = q % CH_A;
      int row = j >> 2, kc = j & 3;
      gsrc[t] = (hl ? Al : Ah) + (size_t)(bm + row) * Kstride + koff + kc * 8;
      loff[t] = ((hl * (BM >> 4) + (row >> 4)) * 4 + kc) * 128 + (row & 15) * 8;
    } else {
      int q2 = q - 2 * CH_A;
      int hl = q2 / CH_B, j = q2 % CH_B;
      int row = j >> 2, kc = j & 3;
      gsrc[t] = (hl ? Bl : Bh) + (size_t)(bn + row) * Kstride + koff + kc * 8;
      loff[t] = 2 * BM * 32 +
                ((hl * (BN >> 4) + (row >> 4)) * 4 + kc) * 128 + (row & 15) * 8;
    }
  }

  f32x4 acc[4][4];
#pragma unroll
  for (int i = 0; i < 4; ++i)
#pragma unroll
    for (int j = 0; j < 4; ++j) acc[i][j] = (f32x4){0.f, 0.f, 0.f, 0.f};

  float4 rbuf[PER];
#pragma unroll
  for (int t = 0; t < PER; ++t) rbuf[t] = *(const float4*)(gsrc[t]);

  for (int k0 = 0; k0 < Klen; k0 += 32) {
#pragma unroll
    for (int t = 0; t < PER; ++t) *(float4*)&sAB[loff[t]] = rbuf[t];
    __syncthreads();

    if (k0 + 32 < Klen) {
#pragma unroll
      for (int t = 0; t < PER; ++t) rbuf[t] = *(const float4*)(gsrc[t] + k0 + 32);
    }

    bf16x8 a_h[4], a_l[4], b_h[4], b_l[4];
#pragma unroll
    for (int i = 0; i < 4; ++i) {
      a_h[i] = *(const bf16x8*)&sAB[((0 * (BM >> 4) + wm * 4 + i) * 4 + lkc) * 128 + lrow * 8];
      a_l[i] = *(const bf16x8*)&sAB[((1 * (BM >> 4) + wm * 4 + i) * 4 + lkc) * 128 + lrow * 8];
      b_h[i] = *(const bf16x8*)&sAB[2 * BM * 32 + ((0 * (BN >> 4) + wn * 4 + i) * 4 + lkc) * 128 + lrow * 8];
      b_l[i] = *(const bf16x8*)&sAB[2 * BM * 32 + ((1 * (BN >> 4) + wn * 4 + i) * 4 + lkc) * 128 + lrow * 8];
    }
#pragma unroll
    for (int i = 0; i < 4; ++i)
#pragma unroll
      for (int j = 0; j < 4; ++j) {
        acc[i][j] = __builtin_amdgcn_mfma_f32_16x16x32_bf16(a_h[i], b_h[j], acc[i][j], 0, 0, 0);
        acc[i][j] = __builtin_amdgcn_mfma_f32_16x16x32_bf16(a_l[i], b_h[j], acc[i][j], 0, 0, 0);
        acc[i][j] = __builtin_amdgcn_mfma_f32_16x16x32_bf16(a_h[i], b_l[j], acc[i][j], 0, 0, 0);
      }
    __syncthreads();
  }

  float* Cs = C + (size_t)blockIdx.z * c_slice;
  const int r0 = (lane >> 4) * 4;
#pragma unroll
  for (int j = 0; j < 4; ++j) {
    int col = bn + wn * 64 + j * 16 + lrow;
    if (col >= N) continue;
    float bv = bias ? bias[col] : 0.f;
#pragma unroll
    for (int i = 0; i < 4; ++i) {
      int rowb = bm + wm * 64 + i * 16 + r0;
#pragma unroll
      for (int r = 0; r < 4; ++r)
        Cs[(size_t)(rowb + r) * ldc + col] = acc[i][j][r] + bv;
    }
  }
}

// ---------------------------------------------------------------------------
// out = sum of 4 split-K partials (float4-vectorized).
// ---------------------------------------------------------------------------
__global__ __launch_bounds__(256)
void reduce4_kernel(const float* __restrict__ p, float* __restrict__ o)
{
  const int n = L_SEQ * 512 / 4;
  int i = blockIdx.x * 256 + threadIdx.x;
  if (i >= n) return;
  float4 a = ((const float4*)p)[i];
  float4 b = ((const float4*)p)[i + n];
  float4 c = ((const float4*)p)[i + 2 * n];
  float4 d = ((const float4*)p)[i + 3 * n];
  float4 r;
  r.x = (a.x + b.x) + (c.x + d.x);
  r.y = (a.y + b.y) + (c.y + d.y);
  r.z = (a.z + b.z) + (c.z + d.z);
  r.w = (a.w + b.w) + (c.w + d.w);
  ((float4*)o)[i] = r;
}

// ---------------------------------------------------------------------------
// dt / lam in EXACT f32 straight from u . W_in rows (bypasses bf16 proj),
// then alpha = exp(dt*A) and u_eff coefficients.
// ---------------------------------------------------------------------------
__global__ __launch_bounds__(256)
void dtlam_kernel(const float* __restrict__ u, const float* __restrict__ W_in,
                  const float* __restrict__ b_in, const float* __restrict__ A_log,
                  float* __restrict__ dtg, float* __restrict__ alphag,
                  float* __restrict__ c0g, float* __restrict__ c1g)
{
  int idx = blockIdx.x * 256 + threadIdx.x;      // L*G = 8192
  if (idx >= L_SEQ * 4) return;
  int l = idx >> 2, g = idx & 3;
  const float4* ur = (const float4*)(u + (size_t)l * 512);
  const float4* wd = (const float4*)(W_in + (size_t)(OFF_DT + g) * 512);
  const float4* wl = (const float4*)(W_in + (size_t)(OFF_DT + 4 + g) * 512);
  float sd = 0.f, sl = 0.f;
  for (int k = 0; k < 128; ++k) {
    float4 a = ur[k], b = wd[k], c = wl[k];
    sd += a.x * b.x + a.y * b.y + a.z * b.z + a.w * b.w;
    sl += a.x * c.x + a.y * c.y + a.z * c.z + a.w * c.w;
  }
  sd += b_in[OFF_DT + g];
  sl += b_in[OFF_DT + 4 + g];
  float dt  = (sd > 20.f) ? sd : log1pf(expf(sd));
  float lam = 1.f / (1.f + expf(-sl));
  float Ag  = -expf(A_log[g]);
  float al  = expf(dt * Ag);
  dtg[idx]    = dt;
  alphag[idx] = al;
  c0g[idx]    = 1.f - lam;
  c1g[idx]    = lam * al;
}

// ---------------------------------------------------------------------------
// f64 inclusive cumsum of dt over L, per group.  grid=4 (g), block=256.
// ---------------------------------------------------------------------------
__global__ __launch_bounds__(256)
void cumsum_dt_kernel(const float* __restrict__ dtg, float* __restrict__ cumdt)
{
  const int g = blockIdx.x;
  const int t = threadIdx.x;
  constexpr int PER = L_SEQ / 256;  // 8
  __shared__ double ps[256];
  float loc[PER];
  double s = 0.0;
  int l0 = t * PER;
  for (int i = 0; i < PER; ++i) {
    loc[i] = dtg[(l0 + i) * 4 + g];
    s += (double)loc[i];
  }
  ps[t] = s;
  __syncthreads();
  for (int off = 1; off < 256; off <<= 1) {
    double v = (t >= off) ? ps[t - off] : 0.0;
    __syncthreads();
    ps[t] += v;
    __syncthreads();
  }
  double c = ps[t] - s;  // exclusive prefix
  for (int i = 0; i < PER; ++i) {
    c += (double)loc[i];
    cumdt[(l0 + i) * 4 + g] = (float)c;
  }
}

// ---------------------------------------------------------------------------
// Per-token: silu(xp) -> xs ; rms+bias+rope for B/C (group level).
// ---------------------------------------------------------------------------
__global__ __launch_bounds__(256)
void pertoken_kernel(const float* __restrict__ proj,
                     const float* __restrict__ cumdt,
                     const float* __restrict__ theta_log,
                     const float* __restrict__ norm_B_w,
                     const float* __restrict__ norm_C_w,
                     const float* __restrict__ bias_B,
                     const float* __restrict__ bias_C,
                     float* __restrict__ xs,
                     float* __restrict__ Brot,
                     float* __restrict__ Crot)
{
  const int l = blockIdx.x;
  const int t = threadIdx.x;
  const size_t prow = (size_t)l * DPROJ;

  for (int i = t; i < 1024; i += 256) {
    float x = proj[prow + OFF_X + i];
    xs[(size_t)l * 1024 + i] = x / (1.f + expf(-x));
  }

  const int g = t >> 6;
  const int e = t & 63;
  float bv = proj[prow + OFF_B + t];
  float cv = proj[prow + OFF_C + t];
  float ssb = bv * bv, ssc = cv * cv;
#pragma unroll
  for (int m = 1; m <= 32; m <<= 1) {
    ssb += __shfl_xor(ssb, m, 64);
    ssc += __shfl_xor(ssc, m, 64);
  }
  float nb = bv * rsqrtf(ssb * (1.f / 64.f) + 1e-5f) * norm_B_w[e] + bias_B[t];
  float nc = cv * rsqrtf(ssc * (1.f / 64.f) + 1e-5f) * norm_C_w[e] + bias_C[t];

  float ang = expf(theta_log[g * 16 + (e >> 2)]) * cumdt[l * 4 + g];
  float ca, sa;
  sincosf(ang, &sa, &ca);   // sincosf writes SIN to 1st ptr, COS to 2nd
  float nb2 = __shfl_xor(nb, 2, 64);
  float nc2 = __shfl_xor(nc, 2, 64);
  bool isre = ((e >> 1) & 1) == 0;
  float Bo, Co;
  if (isre) {
    Bo = nb * ca + nb2 * sa;   // theta = -ang
    Co = nc * ca - nc2 * sa;   // theta = +ang
  } else {
    Bo = nb * ca - nb2 * sa;
    Co = nc * ca + nc2 * sa;
  }
  Brot[(size_t)l * 256 + t] = Bo;
  Crot[(size_t)l * 256 + t] = Co;
}

// ---------------------------------------------------------------------------
// Scan: lane = p, per-thread state H[n=0..31] + uprev[n].
// grid = (NCH, G), block = 256 (4 waves = 4 heads of group g).
// ---------------------------------------------------------------------------
template<bool WITH_Y>
__global__ __launch_bounds__(256)
void scan_chunk(const float* __restrict__ Brot, const float* __restrict__ Crot,
                const float* __restrict__ xup,
                const float* __restrict__ dtg, const float* __restrict__ alphag,
                const float* __restrict__ c0g, const float* __restrict__ c1g,
                const float* __restrict__ hstates_in,
                float* __restrict__ hlast_out, float* __restrict__ y128)
{
  const int c   = blockIdx.x;
  const int g   = blockIdx.y;
  const int wid = threadIdx.x >> 6;
  const int p   = threadIdx.x & 63;
  const int h   = g * 4 + wid;
  const int l0  = c * SCHUNK;

  __shared__ float Bs[SCHUNK][64];
  __shared__ float Cs[SCHUNK][64];
  __shared__ float als[SCHUNK], c0s[SCHUNK], c1s[SCHUNK];

  for (int i = threadIdx.x; i < SCHUNK * 64; i += 256) {
    int l = i >> 6, e = i & 63;
    float dt = dtg[(l0 + l) * 4 + g];
    Bs[l][e] = dt * Brot[(size_t)(l0 + l) * 256 + g * 64 + e];
    if (WITH_Y) Cs[l][e] = Crot[(size_t)(l0 + l) * 256 + g * 64 + e];
  }
  if (threadIdx.x < SCHUNK) {
    int l = threadIdx.x;
    als[l] = alphag[(l0 + l) * 4 + g];
    c0s[l] = c0g[(l0 + l) * 4 + g];
    c1s[l] = c1g[(l0 + l) * 4 + g];
  }
  __syncthreads();

  float H[32], up[32];
  if (WITH_Y) {
    const float* hs = &hstates_in[(((size_t)c * 16 + h) * 64 + p) * 32];
#pragma unroll
    for (int q = 0; q < 8; ++q) {
      float4 v = *reinterpret_cast<const float4*>(hs + 4 * q);
      H[4 * q] = v.x; H[4 * q + 1] = v.y; H[4 * q + 2] = v.z; H[4 * q + 3] = v.w;
    }
  } else {
#pragma unroll
    for (int n = 0; n < 32; ++n) H[n] = 0.f;
  }

  if (c > 0) {
    const int lm = l0 - 1;
    const float dtm = dtg[lm * 4 + g];
    float2 X = *reinterpret_cast<const float2*>(&xup[((size_t)lm * 16 + h) * 128 + 2 * p]);
    float x0 = dtm * X.x, x1 = dtm * X.y;
#pragma unroll
    for (int n = 0; n < 32; ++n) {
      float2 Bv = *reinterpret_cast<const float2*>(&Brot[(size_t)lm * 256 + g * 64 + 2 * n]);
      up[n] = Bv.x * x0 + Bv.y * x1;
    }
  } else {
#pragma unroll
    for (int n = 0; n < 32; ++n) up[n] = 0.f;
  }

  for (int l = 0; l < SCHUNK; ++l) {
    float2 X = *reinterpret_cast<const float2*>(
        &xup[((size_t)(l0 + l) * 16 + h) * 128 + 2 * p]);
    const float al = als[l], cc0 = c0s[l], cc1 = c1s[l];
    float y0 = 0.f, y1 = 0.f;
#pragma unroll
    for (int n2 = 0; n2 < 16; ++n2) {
      float4 Bv = *reinterpret_cast<const float4*>(&Bs[l][4 * n2]);
      float uin0 = Bv.x * X.x + Bv.y * X.y;
      float uin1 = Bv.z * X.x + Bv.w * X.y;
      float ue0 = cc0 * uin0 + cc1 * up[2 * n2];
      float ue1 = cc0 * uin1 + cc1 * up[2 * n2 + 1];
      H[2 * n2]     = al * H[2 * n2]     + ue0;
      H[2 * n2 + 1] = al * H[2 * n2 + 1] + ue1;
      up[2 * n2] = uin0; up[2 * n2 + 1] = uin1;
      if (WITH_Y) {
        float4 Cv = *reinterpret_cast<const float4*>(&Cs[l][4 * n2]);
        y0 = fmaf(H[2 * n2], Cv.x, fmaf(H[2 * n2 + 1], Cv.z, y0));
        y1 = fmaf(H[2 * n2], Cv.y, fmaf(H[2 * n2 + 1], Cv.w, y1));
      }
    }
    if (WITH_Y) {
      *reinterpret_cast<float2*>(&y128[((size_t)(l0 + l) * 16 + h) * 128 + 2 * p]) =
          make_float2(y0, y1);
    }
  }

  if (!WITH_Y) {
    float* hl = &hlast_out[(((size_t)c * 16 + h) * 64 + p) * 32];
#pragma unroll
    for (int q = 0; q < 8; ++q)
      *reinterpret_cast<float4*>(hl + 4 * q) =
          make_float4(H[4 * q], H[4 * q + 1], H[4 * q + 2], H[4 * q + 3]);
  }
}

// ---------------------------------------------------------------------------
// Scan pass B: cross-chunk combine -> h_states (state entering each chunk).
// ---------------------------------------------------------------------------
__global__ __launch_bounds__(256)
void scan_passB(const float* __restrict__ hlast, const float* __restrict__ cumdt,
                const float* __restrict__ A_log, float* __restrict__ hstates)
{
  int idx = blockIdx.x * 256 + threadIdx.x;   // H * P * N = 32768
  int h = idx >> 11;
  int rem = idx & 2047;
  int g = h >> 2;
  float Ag = -expf(A_log[g]);
  float s = 0.f;
  for (int c = 0; c < NCH; ++c) {
    hstates[((size_t)c * 16 + h) * 2048 + rem] = s;
    float sd = cumdt[(c * SCHUNK + SCHUNK - 1) * 4 + g]
             - (c > 0 ? cumdt[(c * SCHUNK - 1) * 4 + g] : 0.f);
    float dec = expf(Ag * sd);
    s = s * dec + hlast[((size_t)c * 16 + h) * 2048 + rem];
  }
}

// ---------------------------------------------------------------------------
// Fuse: yg = (yd + D[h]*xs) * silu(z), in place into proj's z region.
// ---------------------------------------------------------------------------
__global__ __launch_bounds__(256)
void fuse_gate_kernel(const float* __restrict__ yd, const float* __restrict__ xs,
                      const float* __restrict__ Dv, float* __restrict__ proj)
{
  int idx = blockIdx.x * 256 + threadIdx.x;   // L * 1024
  int l = idx >> 10, m = idx & 1023, h = m >> 6;
  float v = yd[((size_t)l * 16 + h) * 64 + (m & 63)] + Dv[h] * xs[idx];
  float z = proj[(size_t)l * DPROJ + m];
  float sz = z / (1.f + expf(-z));
  proj[(size_t)l * DPROJ + m] = v * sz;
}

}  // namespace

extern "C" void kernel_launch(void* const* d_in, const int* in_sizes, int n_in,
                              void* d_out, int out_size, void* d_ws, size_t ws_size,
                              hipStream_t stream)
{
  const float* u         = (const float*)d_in[0];
  const float* W_in      = (const float*)d_in[1];
  const float* b_in      = (const float*)d_in[2];
  const float* W_xup     = (const float*)d_in[3];
  const float* W_ydown   = (const float*)d_in[4];
  const float* A_log     = (const float*)d_in[5];
  const float* theta_log = (const float*)d_in[6];
  const float* Dvec      = (const float*)d_in[7];
  const float* norm_B_w  = (const float*)d_in[8];
  const float* norm_C_w  = (const float*)d_in[9];
  const float* bias_B    = (const float*)d_in[10];
  const float* bias_C    = (const float*)d_in[11];
  const float* W_out     = (const float*)d_in[12];
  float* out = (float*)d_out;

  // ---- f32 workspace carve (floats) ----
  float* proj    = (float*)d_ws;                    // 2048*2568
  float* xs      = proj    + (size_t)L_SEQ * DPROJ; // 2048*1024
  float* dtg     = xs      + (size_t)L_SEQ * 1024;  // 2048*4 each
  float* alphag  = dtg     + L_SEQ * 4;
  float* c0g     = alphag  + L_SEQ * 4;
  float* c1g     = c0g     + L_SEQ * 4;
  float* cumdt   = c1g     + L_SEQ * 4;
  float* Brot    = cumdt   + L_SEQ * 4;             // 2048*256
  float* Crot    = Brot    + (size_t)L_SEQ * 256;
  float* xup     = Crot    + (size_t)L_SEQ * 256;   // 32768*128 (region B)
  float* y128    = xup     + (size_t)32768 * 128;   // 32768*128
  float* yd      = y128    + (size_t)32768 * 128;   // 32768*64
  float* hlast   = y128;                            // alias (dead before y-writes)
  float* hstates = yd;                              // alias (dead before gemm9)
  float* partials = y128;                           // alias: 4*2048*512 = 4.19M fits
                                                    // (y128 f32 dead after its convert)

  // ---- bf16 hi/lo region A (u16), phase-overlaid ----
  u16* rA = (u16*)(yd + (size_t)32768 * 64);
  // phase 1: proj gemm operands
  u16* u_hi   = rA;
  u16* u_lo   = u_hi + (size_t)2048 * 512;
  u16* win_hi = u_lo + (size_t)2048 * 512;          // padded to 2688 rows
  u16* win_lo = win_hi + (size_t)2688 * 512;
  // phase 2: xup gemm operands (after gemm1 done)
  u16* xs_hi   = rA;
  u16* xs_lo   = xs_hi + (size_t)32768 * 64;
  u16* wxup_hi = xs_lo + (size_t)32768 * 64;
  u16* wxup_lo = wxup_hi + (size_t)128 * 64;
  // phase 3: ydown operands (y128 bf16 goes to region B = xup, dead after scans)
  u16* wyd_hi  = rA;
  u16* wyd_lo  = wyd_hi + (size_t)64 * 128;
  u16* y128_hi = (u16*)xup;
  u16* y128_lo = y128_hi + (size_t)32768 * 128;
  // phase 4: out gemm operands (after gemm ydown done)
  u16* yg_hi   = rA;
  u16* yg_lo   = yg_hi + (size_t)2048 * 1024;
  u16* wout_hi = yg_lo + (size_t)2048 * 1024;
  u16* wout_lo = wout_hi + (size_t)512 * 1024;

  // 1. convert u, W_in -> split bf16 ; proj = u @ W_in^T + b_in (MFMA)
  convert_split<<<dim3(1024), 256, 0, stream>>>(u, 2048, 512, 512, 2048, u_hi, u_lo);
  convert_split<<<dim3(1344), 256, 0, stream>>>(W_in, 2568, 512, 512, 2688, win_hi, win_lo);
  gemm_mfma<2, 2, 256><<<dim3(16, 21, 1), 256, 0, stream>>>(
      u_hi, u_lo, win_hi, win_lo, b_in, proj, DPROJ, DPROJ, 512, 512, 0);

  // 2. dt/lam exact-f32 from u . W_in rows; 3. f64 cumsum
  dtlam_kernel<<<dim3(32), 256, 0, stream>>>(u, W_in, b_in, A_log, dtg, alphag, c0g, c1g);
  cumsum_dt_kernel<<<dim3(4), 256, 0, stream>>>(dtg, cumdt);

  // 4. per-token: silu(xp), rms+bias+rope -> Brot/Crot
  pertoken_kernel<<<dim3(L_SEQ), 256, 0, stream>>>(
      proj, cumdt, theta_log, norm_B_w, norm_C_w, bias_B, bias_C, xs, Brot, Crot);

  // 5. x_up = xs @ W_xup^T (MFMA)
  convert_split<<<dim3(2048), 256, 0, stream>>>(xs, 32768, 64, 64, 32768, xs_hi, xs_lo);
  convert_split<<<dim3(8), 256, 0, stream>>>(W_xup, 128, 64, 64, 128, wxup_hi, wxup_lo);
  gemm_mfma<2, 2, 256><<<dim3(256, 1, 1), 256, 0, stream>>>(
      xs_hi, xs_lo, wxup_hi, wxup_lo, nullptr, xup, 128, 128, 64, 64, 0);

  // 6-8. chunked scan (state-in-registers)
  scan_chunk<false><<<dim3(NCH, 4), 256, 0, stream>>>(
      Brot, Crot, xup, dtg, alphag, c0g, c1g, nullptr, hlast, nullptr);
  scan_passB<<<dim3(128), 256, 0, stream>>>(hlast, cumdt, A_log, hstates);
  scan_chunk<true><<<dim3(NCH, 4), 256, 0, stream>>>(
      Brot, Crot, xup, dtg, alphag, c0g, c1g, hstates, nullptr, y128);

  // 9. yd = y128 @ W_ydown^T (MFMA); y128 bf16 into dead xup region
  convert_split<<<dim3(4096), 256, 0, stream>>>(y128, 32768, 128, 128, 32768, y128_hi, y128_lo);
  convert_split<<<dim3(8), 256, 0, stream>>>(W_ydown, 64, 128, 128, 64, wyd_hi, wyd_lo);
  gemm_mfma<2, 1, 128><<<dim3(256, 1, 1), 128, 0, stream>>>(
      y128_hi, y128_lo, wyd_hi, wyd_lo, nullptr, yd, 64, 64, 128, 128, 0);

  // 10. gate: yg = (yd + D*xs) * silu(z), in place into proj[:, 0:1024]
  fuse_gate_kernel<<<dim3(8192), 256, 0, stream>>>(yd, xs, Dvec, proj);

  // 11. out = yg @ W_out^T (MFMA, split-K=4 into partials) ; reduce
  convert_split<<<dim3(2048), 256, 0, stream>>>(proj, 2048, 1024, DPROJ, 2048, yg_hi, yg_lo);
  convert_split<<<dim3(512), 256, 0, stream>>>(W_out, 512, 1024, 1024, 512, wout_hi, wout_lo);
  gemm_mfma<2, 2, 256><<<dim3(16, 4, 4), 256, 0, stream>>>(
      yg_hi, yg_lo, wout_hi, wout_lo, nullptr, partials, 512, 512, 1024, 256,
      (size_t)L_SEQ * 512);
  reduce4_kernel<<<dim3(1024), 256, 0, stream>>>(partials, out);
}

// Round 8
// 225.888 us; speedup vs baseline: 1.8457x; 1.3512x over previous
//
#include <hip/hip_runtime.h>
#include <hip/hip_bf16.h>
#include <math.h>

namespace {

typedef unsigned short u16;
typedef __bf16 bf16x8 __attribute__((ext_vector_type(8)));
typedef float f32x4 __attribute__((ext_vector_type(4)));

constexpr int L_SEQ  = 2048;
constexpr int DPROJ  = 2568;
constexpr int OFF_X  = 1024;
constexpr int OFF_B  = 2048;
constexpr int OFF_C  = 2304;
constexpr int OFF_DT = 2560;
constexpr int SCHUNK = 32;
constexpr int NCH    = L_SEQ / SCHUNK;  // 64

// ---------------------------------------------------------------------------
// f32 -> (bf16 hi, bf16 lo) split conversion. Pads rows to rows_pad w/ zeros.
// ---------------------------------------------------------------------------
__device__ inline u16 f2bf(float x) {
  unsigned u = __float_as_uint(x);
  unsigned r = u + 0x7FFFu + ((u >> 16) & 1u);
  return (u16)(r >> 16);
}

__global__ __launch_bounds__(256)
void convert_split(const float* __restrict__ src, int rows, int cols, int stride,
                   int rows_pad, u16* __restrict__ hi, u16* __restrict__ lo)
{
  int idx = blockIdx.x * 256 + threadIdx.x;
  int c4cnt = cols >> 2;
  if (idx >= rows_pad * c4cnt) return;
  int row = idx / c4cnt;
  int c4  = (idx % c4cnt) << 2;
  float4 v = make_float4(0.f, 0.f, 0.f, 0.f);
  if (row < rows) v = *(const float4*)(src + (size_t)row * stride + c4);
  float x[4] = {v.x, v.y, v.z, v.w};
  u16 h[4], l[4];
#pragma unroll
  for (int j = 0; j < 4; ++j) {
    h[j] = f2bf(x[j]);
    float hf = __uint_as_float(((unsigned)h[j]) << 16);
    l[j] = f2bf(x[j] - hf);
  }
  size_t off = (size_t)row * cols + c4;
  *(ushort4*)(hi + off) = make_ushort4(h[0], h[1], h[2], h[3]);
  *(ushort4*)(lo + off) = make_ushort4(l[0], l[1], l[2], l[3]);
}

// ---------------------------------------------------------------------------
// async global->LDS, 16B per lane. LDS dest is wave-uniform base + lane*16.
// ---------------------------------------------------------------------------
__device__ inline void gload16(const u16* g, u16* l) {
  __builtin_amdgcn_global_load_lds(
      (const __attribute__((address_space(1))) unsigned int*)g,
      (__attribute__((address_space(3))) unsigned int*)l, 16, 0, 0);
}

// ---------------------------------------------------------------------------
// Split-bf16 MFMA GEMM: C[M,N] = A[M,K] * B[N,K]^T (+bias).
// Wave computes 64x64 (4x4 frags of 16x16x32). A*B ~= Ah*Bh + Al*Bh + Ah*Bl.
// Staging: global_load_lds (no VGPR round-trip, no spill). LDS linear order
// IS fragment order: group g (one hi-or-lo 16-row subtile) occupies bytes
// [g*1024, g*1024+1024); within it row r, kchunk kc at r*64 + kc*16. The
// staging call's per-lane global address is pre-swizzled (lane l -> row l>>2,
// kc l&3) so lanes 0-3 read 64B contiguous. Frag ds_read_b128 spans a
// contiguous 1KB per wave -> conflict-free.
// Double-buffered LDS, 2-phase: STAGE(next) || MFMA(cur), one barrier/k-step.
// Split-K via blockIdx.z writing to C + z*c_slice.
// ---------------------------------------------------------------------------
template<int WMW, int WNW>
__global__ __launch_bounds__(64 * WMW * WNW)
void gemm_mfma(const u16* __restrict__ Ah, const u16* __restrict__ Al,
               const u16* __restrict__ Bh, const u16* __restrict__ Bl,
               const float* __restrict__ bias,
               float* __restrict__ C, int ldc, int N,
               int Kstride, int Klen, size_t c_slice)
{
  constexpr int BM = 64 * WMW, BN = 64 * WNW;
  constexpr int WAVES = WMW * WNW;
  constexpr int RG_A = BM / 16, RG_B = BN / 16;
  constexpr int NG = 2 * RG_A + 2 * RG_B;      // 16-row groups per k-step
  constexpr int GPW = NG / WAVES;              // groups staged per wave
  static_assert(NG % WAVES == 0, "");

  __shared__ u16 sAB[2][NG * 512];             // NG KB per buffer

  const int tid  = threadIdx.x;
  const int wave = tid >> 6;
  const int lane = tid & 63;
  const int wm   = wave % WMW;
  const int wn   = wave / WMW;
  const int bm   = blockIdx.x * BM;
  const int bn   = blockIdx.y * BN;
  const int koff = blockIdx.z * Klen;
  const int lrow = lane & 15;                  // frag-read row
  const int lkc  = lane >> 4;                  // frag-read k-chunk
  const int sr   = lane >> 2;                  // stage row within group
  const int sk8  = (lane & 3) * 8;             // stage k offset (u16)

  // Per-lane global base pointer for each staged group (k-independent).
  const u16* gptr[GPW];
#pragma unroll
  for (int t = 0; t < GPW; ++t) {
    int g = wave * GPW + t;
    const u16* base;
    int rowbase;
    if (g < 2 * RG_A) {
      int hl = g / RG_A, i = g % RG_A;
      base = hl ? Al : Ah;  rowbase = bm + i * 16;
    } else {
      int g2 = g - 2 * RG_A;
      int hl = g2 / RG_B, i = g2 % RG_B;
      base = hl ? Bl : Bh;  rowbase = bn + i * 16;
    }
    gptr[t] = base + (size_t)(rowbase + sr) * Kstride + koff + sk8;
  }

  f32x4 acc[4][4];
#pragma unroll
  for (int i = 0; i < 4; ++i)
#pragma unroll
    for (int j = 0; j < 4; ++j) acc[i][j] = (f32x4){0.f, 0.f, 0.f, 0.f};

#define STAGE(b, kk)                                             \
  {                                                              \
    _Pragma("unroll")                                            \
    for (int t = 0; t < GPW; ++t)                                \
      gload16(gptr[t] + (kk), &sAB[b][(wave * GPW + t) * 512]);  \
  }

  STAGE(0, 0);
  asm volatile("s_waitcnt vmcnt(0)" ::: "memory");
  __syncthreads();

  int buf = 0;
  for (int k0 = 0; k0 < Klen; k0 += 32) {
    if (k0 + 32 < Klen) STAGE(buf ^ 1, k0 + 32);

    const u16* sb = sAB[buf];
    bf16x8 a_h[4], a_l[4], b_h[4], b_l[4];
#pragma unroll
    for (int i = 0; i < 4; ++i) {
      a_h[i] = *(const bf16x8*)&sb[(0 * RG_A + wm * 4 + i) * 512 + lrow * 32 + lkc * 8];
      a_l[i] = *(const bf16x8*)&sb[(1 * RG_A + wm * 4 + i) * 512 + lrow * 32 + lkc * 8];
      b_h[i] = *(const bf16x8*)&sb[(2 * RG_A + 0 * RG_B + wn * 4 + i) * 512 + lrow * 32 + lkc * 8];
      b_l[i] = *(const bf16x8*)&sb[(2 * RG_A + 1 * RG_B + wn * 4 + i) * 512 + lrow * 32 + lkc * 8];
    }
#pragma unroll
    for (int i = 0; i < 4; ++i)
#pragma unroll
      for (int j = 0; j < 4; ++j) {
        acc[i][j] = __builtin_amdgcn_mfma_f32_16x16x32_bf16(a_h[i], b_h[j], acc[i][j], 0, 0, 0);
        acc[i][j] = __builtin_amdgcn_mfma_f32_16x16x32_bf16(a_l[i], b_h[j], acc[i][j], 0, 0, 0);
        acc[i][j] = __builtin_amdgcn_mfma_f32_16x16x32_bf16(a_h[i], b_l[j], acc[i][j], 0, 0, 0);
      }

    asm volatile("s_waitcnt vmcnt(0)" ::: "memory");
    __syncthreads();
    buf ^= 1;
  }
#undef STAGE

  float* Cs = C + (size_t)blockIdx.z * c_slice;
  const int r0 = (lane >> 4) * 4;
#pragma unroll
  for (int j = 0; j < 4; ++j) {
    int col = bn + wn * 64 + j * 16 + lrow;
    if (col >= N) continue;
    float bv = bias ? bias[col] : 0.f;
#pragma unroll
    for (int i = 0; i < 4; ++i) {
      int rowb = bm + wm * 64 + i * 16 + r0;
#pragma unroll
      for (int r = 0; r < 4; ++r)
        Cs[(size_t)(rowb + r) * ldc + col] = acc[i][j][r] + bv;
    }
  }
}

// ---------------------------------------------------------------------------
// out = sum of 4 split-K partials (float4-vectorized).
// ---------------------------------------------------------------------------
__global__ __launch_bounds__(256)
void reduce4_kernel(const float* __restrict__ p, float* __restrict__ o)
{
  const int n = L_SEQ * 512 / 4;
  int i = blockIdx.x * 256 + threadIdx.x;
  if (i >= n) return;
  float4 a = ((const float4*)p)[i];
  float4 b = ((const float4*)p)[i + n];
  float4 c = ((const float4*)p)[i + 2 * n];
  float4 d = ((const float4*)p)[i + 3 * n];
  float4 r;
  r.x = (a.x + b.x) + (c.x + d.x);
  r.y = (a.y + b.y) + (c.y + d.y);
  r.z = (a.z + b.z) + (c.z + d.z);
  r.w = (a.w + b.w) + (c.w + d.w);
  ((float4*)o)[i] = r;
}

// ---------------------------------------------------------------------------
// dt / lam in EXACT f32 straight from u . W_in rows (bypasses bf16 proj),
// then alpha = exp(dt*A) and u_eff coefficients.
// ---------------------------------------------------------------------------
__global__ __launch_bounds__(256)
void dtlam_kernel(const float* __restrict__ u, const float* __restrict__ W_in,
                  const float* __restrict__ b_in, const float* __restrict__ A_log,
                  float* __restrict__ dtg, float* __restrict__ alphag,
                  float* __restrict__ c0g, float* __restrict__ c1g)
{
  int idx = blockIdx.x * 256 + threadIdx.x;      // L*G = 8192
  if (idx >= L_SEQ * 4) return;
  int l = idx >> 2, g = idx & 3;
  const float4* ur = (const float4*)(u + (size_t)l * 512);
  const float4* wd = (const float4*)(W_in + (size_t)(OFF_DT + g) * 512);
  const float4* wl = (const float4*)(W_in + (size_t)(OFF_DT + 4 + g) * 512);
  float sd = 0.f, sl = 0.f;
  for (int k = 0; k < 128; ++k) {
    float4 a = ur[k], b = wd[k], c = wl[k];
    sd += a.x * b.x + a.y * b.y + a.z * b.z + a.w * b.w;
    sl += a.x * c.x + a.y * c.y + a.z * c.z + a.w * c.w;
  }
  sd += b_in[OFF_DT + g];
  sl += b_in[OFF_DT + 4 + g];
  float dt  = (sd > 20.f) ? sd : log1pf(expf(sd));
  float lam = 1.f / (1.f + expf(-sl));
  float Ag  = -expf(A_log[g]);
  float al  = expf(dt * Ag);
  dtg[idx]    = dt;
  alphag[idx] = al;
  c0g[idx]    = 1.f - lam;
  c1g[idx]    = lam * al;
}

// ---------------------------------------------------------------------------
// f64 inclusive cumsum of dt over L, per group.  grid=4 (g), block=256.
// ---------------------------------------------------------------------------
__global__ __launch_bounds__(256)
void cumsum_dt_kernel(const float* __restrict__ dtg, float* __restrict__ cumdt)
{
  const int g = blockIdx.x;
  const int t = threadIdx.x;
  constexpr int PER = L_SEQ / 256;  // 8
  __shared__ double ps[256];
  float loc[PER];
  double s = 0.0;
  int l0 = t * PER;
  for (int i = 0; i < PER; ++i) {
    loc[i] = dtg[(l0 + i) * 4 + g];
    s += (double)loc[i];
  }
  ps[t] = s;
  __syncthreads();
  for (int off = 1; off < 256; off <<= 1) {
    double v = (t >= off) ? ps[t - off] : 0.0;
    __syncthreads();
    ps[t] += v;
    __syncthreads();
  }
  double c = ps[t] - s;  // exclusive prefix
  for (int i = 0; i < PER; ++i) {
    c += (double)loc[i];
    cumdt[(l0 + i) * 4 + g] = (float)c;
  }
}

// ---------------------------------------------------------------------------
// Per-token: silu(xp) -> xs ; rms+bias+rope for B/C (group level).
// ---------------------------------------------------------------------------
__global__ __launch_bounds__(256)
void pertoken_kernel(const float* __restrict__ proj,
                     const float* __restrict__ cumdt,
                     const float* __restrict__ theta_log,
                     const float* __restrict__ norm_B_w,
                     const float* __restrict__ norm_C_w,
                     const float* __restrict__ bias_B,
                     const float* __restrict__ bias_C,
                     float* __restrict__ xs,
                     float* __restrict__ Brot,
                     float* __restrict__ Crot)
{
  const int l = blockIdx.x;
  const int t = threadIdx.x;
  const size_t prow = (size_t)l * DPROJ;

  for (int i = t; i < 1024; i += 256) {
    float x = proj[prow + OFF_X + i];
    xs[(size_t)l * 1024 + i] = x / (1.f + expf(-x));
  }

  const int g = t >> 6;
  const int e = t & 63;
  float bv = proj[prow + OFF_B + t];
  float cv = proj[prow + OFF_C + t];
  float ssb = bv * bv, ssc = cv * cv;
#pragma unroll
  for (int m = 1; m <= 32; m <<= 1) {
    ssb += __shfl_xor(ssb, m, 64);
    ssc += __shfl_xor(ssc, m, 64);
  }
  float nb = bv * rsqrtf(ssb * (1.f / 64.f) + 1e-5f) * norm_B_w[e] + bias_B[t];
  float nc = cv * rsqrtf(ssc * (1.f / 64.f) + 1e-5f) * norm_C_w[e] + bias_C[t];

  float ang = expf(theta_log[g * 16 + (e >> 2)]) * cumdt[l * 4 + g];
  float ca, sa;
  sincosf(ang, &sa, &ca);   // sincosf writes SIN to 1st ptr, COS to 2nd
  float nb2 = __shfl_xor(nb, 2, 64);
  float nc2 = __shfl_xor(nc, 2, 64);
  bool isre = ((e >> 1) & 1) == 0;
  float Bo, Co;
  if (isre) {
    Bo = nb * ca + nb2 * sa;   // theta = -ang
    Co = nc * ca - nc2 * sa;   // theta = +ang
  } else {
    Bo = nb * ca - nb2 * sa;
    Co = nc * ca + nc2 * sa;
  }
  Brot[(size_t)l * 256 + t] = Bo;
  Crot[(size_t)l * 256 + t] = Co;
}

// ---------------------------------------------------------------------------
// Scan: lane = p, per-thread state H[n=0..31] + uprev[n].
// grid = (NCH, G), block = 256 (4 waves = 4 heads of group g).
// ---------------------------------------------------------------------------
template<bool WITH_Y>
__global__ __launch_bounds__(256)
void scan_chunk(const float* __restrict__ Brot, const float* __restrict__ Crot,
                const float* __restrict__ xup,
                const float* __restrict__ dtg, const float* __restrict__ alphag,
                const float* __restrict__ c0g, const float* __restrict__ c1g,
                const float* __restrict__ hstates_in,
                float* __restrict__ hlast_out, float* __restrict__ y128)
{
  const int c   = blockIdx.x;
  const int g   = blockIdx.y;
  const int wid = threadIdx.x >> 6;
  const int p   = threadIdx.x & 63;
  const int h   = g * 4 + wid;
  const int l0  = c * SCHUNK;

  __shared__ float Bs[SCHUNK][64];
  __shared__ float Cs[SCHUNK][64];
  __shared__ float als[SCHUNK], c0s[SCHUNK], c1s[SCHUNK];

  for (int i = threadIdx.x; i < SCHUNK * 64; i += 256) {
    int l = i >> 6, e = i & 63;
    float dt = dtg[(l0 + l) * 4 + g];
    Bs[l][e] = dt * Brot[(size_t)(l0 + l) * 256 + g * 64 + e];
    if (WITH_Y) Cs[l][e] = Crot[(size_t)(l0 + l) * 256 + g * 64 + e];
  }
  if (threadIdx.x < SCHUNK) {
    int l = threadIdx.x;
    als[l] = alphag[(l0 + l) * 4 + g];
    c0s[l] = c0g[(l0 + l) * 4 + g];
    c1s[l] = c1g[(l0 + l) * 4 + g];
  }
  __syncthreads();

  float H[32], up[32];
  if (WITH_Y) {
    const float* hs = &hstates_in[(((size_t)c * 16 + h) * 64 + p) * 32];
#pragma unroll
    for (int q = 0; q < 8; ++q) {
      float4 v = *reinterpret_cast<const float4*>(hs + 4 * q);
      H[4 * q] = v.x; H[4 * q + 1] = v.y; H[4 * q + 2] = v.z; H[4 * q + 3] = v.w;
    }
  } else {
#pragma unroll
    for (int n = 0; n < 32; ++n) H[n] = 0.f;
  }

  if (c > 0) {
    const int lm = l0 - 1;
    const float dtm = dtg[lm * 4 + g];
    float2 X = *reinterpret_cast<const float2*>(&xup[((size_t)lm * 16 + h) * 128 + 2 * p]);
    float x0 = dtm * X.x, x1 = dtm * X.y;
#pragma unroll
    for (int n = 0; n < 32; ++n) {
      float2 Bv = *reinterpret_cast<const float2*>(&Brot[(size_t)lm * 256 + g * 64 + 2 * n]);
      up[n] = Bv.x * x0 + Bv.y * x1;
    }
  } else {
#pragma unroll
    for (int n = 0; n < 32; ++n) up[n] = 0.f;
  }

  for (int l = 0; l < SCHUNK; ++l) {
    float2 X = *reinterpret_cast<const float2*>(
        &xup[((size_t)(l0 + l) * 16 + h) * 128 + 2 * p]);
    const float al = als[l], cc0 = c0s[l], cc1 = c1s[l];
    float y0 = 0.f, y1 = 0.f;
#pragma unroll
    for (int n2 = 0; n2 < 16; ++n2) {
      float4 Bv = *reinterpret_cast<const float4*>(&Bs[l][4 * n2]);
      float uin0 = Bv.x * X.x + Bv.y * X.y;
      float uin1 = Bv.z * X.x + Bv.w * X.y;
      float ue0 = cc0 * uin0 + cc1 * up[2 * n2];
      float ue1 = cc0 * uin1 + cc1 * up[2 * n2 + 1];
      H[2 * n2]     = al * H[2 * n2]     + ue0;
      H[2 * n2 + 1] = al * H[2 * n2 + 1] + ue1;
      up[2 * n2] = uin0; up[2 * n2 + 1] = uin1;
      if (WITH_Y) {
        float4 Cv = *reinterpret_cast<const float4*>(&Cs[l][4 * n2]);
        y0 = fmaf(H[2 * n2], Cv.x, fmaf(H[2 * n2 + 1], Cv.z, y0));
        y1 = fmaf(H[2 * n2], Cv.y, fmaf(H[2 * n2 + 1], Cv.w, y1));
      }
    }
    if (WITH_Y) {
      *reinterpret_cast<float2*>(&y128[((size_t)(l0 + l) * 16 + h) * 128 + 2 * p]) =
          make_float2(y0, y1);
    }
  }

  if (!WITH_Y) {
    float* hl = &hlast_out[(((size_t)c * 16 + h) * 64 + p) * 32];
#pragma unroll
    for (int q = 0; q < 8; ++q)
      *reinterpret_cast<float4*>(hl + 4 * q) =
          make_float4(H[4 * q], H[4 * q + 1], H[4 * q + 2], H[4 * q + 3]);
  }
}

// ---------------------------------------------------------------------------
// Scan pass B: cross-chunk combine -> h_states (state entering each chunk).
// ---------------------------------------------------------------------------
__global__ __launch_bounds__(256)
void scan_passB(const float* __restrict__ hlast, const float* __restrict__ cumdt,
                const float* __restrict__ A_log, float* __restrict__ hstates)
{
  int idx = blockIdx.x * 256 + threadIdx.x;   // H * P * N = 32768
  int h = idx >> 11;
  int rem = idx & 2047;
  int g = h >> 2;
  float Ag = -expf(A_log[g]);
  float s = 0.f;
  for (int c = 0; c < NCH; ++c) {
    hstates[((size_t)c * 16 + h) * 2048 + rem] = s;
    float sd = cumdt[(c * SCHUNK + SCHUNK - 1) * 4 + g]
             - (c > 0 ? cumdt[(c * SCHUNK - 1) * 4 + g] : 0.f);
    float dec = expf(Ag * sd);
    s = s * dec + hlast[((size_t)c * 16 + h) * 2048 + rem];
  }
}

// ---------------------------------------------------------------------------
// Fuse: yg = (yd + D[h]*xs) * silu(z), in place into proj's z region.
// ---------------------------------------------------------------------------
__global__ __launch_bounds__(256)
void fuse_gate_kernel(const float* __restrict__ yd, const float* __restrict__ xs,
                      const float* __restrict__ Dv, float* __restrict__ proj)
{
  int idx = blockIdx.x * 256 + threadIdx.x;   // L * 1024
  int l = idx >> 10, m = idx & 1023, h = m >> 6;
  float v = yd[((size_t)l * 16 + h) * 64 + (m & 63)] + Dv[h] * xs[idx];
  float z = proj[(size_t)l * DPROJ + m];
  float sz = z / (1.f + expf(-z));
  proj[(size_t)l * DPROJ + m] = v * sz;
}

}  // namespace

extern "C" void kernel_launch(void* const* d_in, const int* in_sizes, int n_in,
                              void* d_out, int out_size, void* d_ws, size_t ws_size,
                              hipStream_t stream)
{
  const float* u         = (const float*)d_in[0];
  const float* W_in      = (const float*)d_in[1];
  const float* b_in      = (const float*)d_in[2];
  const float* W_xup     = (const float*)d_in[3];
  const float* W_ydown   = (const float*)d_in[4];
  const float* A_log     = (const float*)d_in[5];
  const float* theta_log = (const float*)d_in[6];
  const float* Dvec      = (const float*)d_in[7];
  const float* norm_B_w  = (const float*)d_in[8];
  const float* norm_C_w  = (const float*)d_in[9];
  const float* bias_B    = (const float*)d_in[10];
  const float* bias_C    = (const float*)d_in[11];
  const float* W_out     = (const float*)d_in[12];
  float* out = (float*)d_out;

  // ---- f32 workspace carve (floats) ----
  float* proj    = (float*)d_ws;                    // 2048*2568
  float* xs      = proj    + (size_t)L_SEQ * DPROJ; // 2048*1024
  float* dtg     = xs      + (size_t)L_SEQ * 1024;  // 2048*4 each
  float* alphag  = dtg     + L_SEQ * 4;
  float* c0g     = alphag  + L_SEQ * 4;
  float* c1g     = c0g     + L_SEQ * 4;
  float* cumdt   = c1g     + L_SEQ * 4;
  float* Brot    = cumdt   + L_SEQ * 4;             // 2048*256
  float* Crot    = Brot    + (size_t)L_SEQ * 256;
  float* xup     = Crot    + (size_t)L_SEQ * 256;   // 32768*128 (region B)
  float* y128    = xup     + (size_t)32768 * 128;   // 32768*128
  float* yd      = y128    + (size_t)32768 * 128;   // 32768*64
  float* hlast   = y128;                            // alias (dead before y-writes)
  float* hstates = yd;                              // alias (dead before gemm9)
  float* partials = y128;                           // alias: 4*2048*512 fits

  // ---- bf16 hi/lo region A (u16), phase-overlaid ----
  u16* rA = (u16*)(yd + (size_t)32768 * 64);
  // phase 1: proj gemm operands
  u16* u_hi   = rA;
  u16* u_lo   = u_hi + (size_t)2048 * 512;
  u16* win_hi = u_lo + (size_t)2048 * 512;          // padded to 2688 rows
  u16* win_lo = win_hi + (size_t)2688 * 512;
  // phase 2: xup gemm operands (after gemm1 done)
  u16* xs_hi   = rA;
  u16* xs_lo   = xs_hi + (size_t)32768 * 64;
  u16* wxup_hi = xs_lo + (size_t)32768 * 64;
  u16* wxup_lo = wxup_hi + (size_t)128 * 64;
  // phase 3: ydown operands (y128 bf16 goes to region B = xup, dead after scans)
  u16* wyd_hi  = rA;
  u16* wyd_lo  = wyd_hi + (size_t)64 * 128;
  u16* y128_hi = (u16*)xup;
  u16* y128_lo = y128_hi + (size_t)32768 * 128;
  // phase 4: out gemm operands (after gemm ydown done)
  u16* yg_hi   = rA;
  u16* yg_lo   = yg_hi + (size_t)2048 * 1024;
  u16* wout_hi = yg_lo + (size_t)2048 * 1024;
  u16* wout_lo = wout_hi + (size_t)512 * 1024;

  // 1. convert u, W_in -> split bf16 ; proj = u @ W_in^T + b_in (MFMA)
  convert_split<<<dim3(1024), 256, 0, stream>>>(u, 2048, 512, 512, 2048, u_hi, u_lo);
  convert_split<<<dim3(1344), 256, 0, stream>>>(W_in, 2568, 512, 512, 2688, win_hi, win_lo);
  gemm_mfma<2, 2><<<dim3(16, 21, 1), 256, 0, stream>>>(
      u_hi, u_lo, win_hi, win_lo, b_in, proj, DPROJ, DPROJ, 512, 512, 0);

  // 2. dt/lam exact-f32 from u . W_in rows; 3. f64 cumsum
  dtlam_kernel<<<dim3(32), 256, 0, stream>>>(u, W_in, b_in, A_log, dtg, alphag, c0g, c1g);
  cumsum_dt_kernel<<<dim3(4), 256, 0, stream>>>(dtg, cumdt);

  // 4. per-token: silu(xp), rms+bias+rope -> Brot/Crot
  pertoken_kernel<<<dim3(L_SEQ), 256, 0, stream>>>(
      proj, cumdt, theta_log, norm_B_w, norm_C_w, bias_B, bias_C, xs, Brot, Crot);

  // 5. x_up = xs @ W_xup^T (MFMA)
  convert_split<<<dim3(2048), 256, 0, stream>>>(xs, 32768, 64, 64, 32768, xs_hi, xs_lo);
  convert_split<<<dim3(8), 256, 0, stream>>>(W_xup, 128, 64, 64, 128, wxup_hi, wxup_lo);
  gemm_mfma<2, 2><<<dim3(256, 1, 1), 256, 0, stream>>>(
      xs_hi, xs_lo, wxup_hi, wxup_lo, nullptr, xup, 128, 128, 64, 64, 0);

  // 6-8. chunked scan (state-in-registers)
  scan_chunk<false><<<dim3(NCH, 4), 256, 0, stream>>>(
      Brot, Crot, xup, dtg, alphag, c0g, c1g, nullptr, hlast, nullptr);
  scan_passB<<<dim3(128), 256, 0, stream>>>(hlast, cumdt, A_log, hstates);
  scan_chunk<true><<<dim3(NCH, 4), 256, 0, stream>>>(
      Brot, Crot, xup, dtg, alphag, c0g, c1g, hstates, nullptr, y128);

  // 9. yd = y128 @ W_ydown^T (MFMA); y128 bf16 into dead xup region
  convert_split<<<dim3(4096), 256, 0, stream>>>(y128, 32768, 128, 128, 32768, y128_hi, y128_lo);
  convert_split<<<dim3(8), 256, 0, stream>>>(W_ydown, 64, 128, 128, 64, wyd_hi, wyd_lo);
  gemm_mfma<2, 1><<<dim3(256, 1, 1), 128, 0, stream>>>(
      y128_hi, y128_lo, wyd_hi, wyd_lo, nullptr, yd, 64, 64, 128, 128, 0);

  // 10. gate: yg = (yd + D*xs) * silu(z), in place into proj[:, 0:1024]
  fuse_gate_kernel<<<dim3(8192), 256, 0, stream>>>(yd, xs, Dvec, proj);

  // 11. out = yg @ W_out^T (MFMA, split-K=4 into partials) ; reduce
  convert_split<<<dim3(2048), 256, 0, stream>>>(proj, 2048, 1024, DPROJ, 2048, yg_hi, yg_lo);
  convert_split<<<dim3(512), 256, 0, stream>>>(W_out, 512, 1024, 1024, 512, wout_hi, wout_lo);
  gemm_mfma<2, 2><<<dim3(16, 4, 4), 256, 0, stream>>>(
      yg_hi, yg_lo, wout_hi, wout_lo, nullptr, partials, 512, 512, 1024, 256,
      (size_t)L_SEQ * 512);
  reduce4_kernel<<<dim3(1024), 256, 0, stream>>>(partials, out);
}

// Round 9
// 208.656 us; speedup vs baseline: 1.9982x; 1.0826x over previous
//
#include <hip/hip_runtime.h>
#include <hip/hip_bf16.h>
#include <math.h>

namespace {

typedef unsigned short u16;
typedef __bf16 bf16x8 __attribute__((ext_vector_type(8)));
typedef float f32x4 __attribute__((ext_vector_type(4)));

constexpr int L_SEQ  = 2048;
constexpr int DPROJ  = 2568;
constexpr int OFF_X  = 1024;
constexpr int OFF_B  = 2048;
constexpr int OFF_C  = 2304;
constexpr int OFF_DT = 2560;
constexpr int SCHUNK = 32;
constexpr int NCH    = L_SEQ / SCHUNK;  // 64

__device__ inline u16 f2bf(float x) {
  unsigned u = __float_as_uint(x);
  unsigned r = u + 0x7FFFu + ((u >> 16) & 1u);
  return (u16)(r >> 16);
}
__device__ inline float bf2f(u16 h) {
  return __uint_as_float(((unsigned)h) << 16);
}

// ---------------------------------------------------------------------------
// f32 -> (bf16 hi, bf16 lo) split conversion. Pads rows to rows_pad w/ zeros.
// ---------------------------------------------------------------------------
__global__ __launch_bounds__(256)
void convert_split(const float* __restrict__ src, int rows, int cols, int stride,
                   int rows_pad, u16* __restrict__ hi, u16* __restrict__ lo)
{
  int idx = blockIdx.x * 256 + threadIdx.x;
  int c4cnt = cols >> 2;
  if (idx >= rows_pad * c4cnt) return;
  int row = idx / c4cnt;
  int c4  = (idx % c4cnt) << 2;
  float4 v = make_float4(0.f, 0.f, 0.f, 0.f);
  if (row < rows) v = *(const float4*)(src + (size_t)row * stride + c4);
  float x[4] = {v.x, v.y, v.z, v.w};
  u16 h[4], l[4];
#pragma unroll
  for (int j = 0; j < 4; ++j) {
    h[j] = f2bf(x[j]);
    l[j] = f2bf(x[j] - bf2f(h[j]));
  }
  size_t off = (size_t)row * cols + c4;
  *(ushort4*)(hi + off) = make_ushort4(h[0], h[1], h[2], h[3]);
  *(ushort4*)(lo + off) = make_ushort4(l[0], l[1], l[2], l[3]);
}

// ---------------------------------------------------------------------------
// async global->LDS, 16B per lane.
// ---------------------------------------------------------------------------
__device__ inline void gload16(const u16* g, u16* l) {
  __builtin_amdgcn_global_load_lds(
      (const __attribute__((address_space(1))) unsigned int*)g,
      (__attribute__((address_space(3))) unsigned int*)l, 16, 0, 0);
}

// XCD-aware bijective swizzle (requires nwg % 8 == 0; all our grids comply).
__device__ inline void xcd_swizzle(int& bx, int& by, int& bz) {
  int nx = gridDim.x, ny = gridDim.y;
  int nwg = nx * ny * gridDim.z;
  int flat = blockIdx.x + nx * (blockIdx.y + ny * blockIdx.z);
  int cpx = nwg >> 3;
  int swz = (flat & 7) * cpx + (flat >> 3);
  bx = swz % nx;
  int r = swz / nx;
  by = r % ny;
  bz = r / ny;
}

// ---------------------------------------------------------------------------
// Split-bf16 MFMA GEMM: C[M,N] = A[M,K] * B[N,K]^T (+bias).
// Wave computes 64x64 (4x4 frags of 16x16x32). A*B ~= Ah*Bh + Al*Bh + Ah*Bl.
// global_load_lds staging into fragment-ordered LDS (conflict-free), double
// buffered. GATE=true: ydown-specific fused epilogue
//   yg[l,h*64+p] = (acc + D[h]*xs[l,h*64+p]) * silu(proj[l,h*64+p])
// written as bf16 hi/lo split (rows = l*16+h, cols = p).
// ---------------------------------------------------------------------------
template<int WMW, int WNW, bool GATE>
__global__ __launch_bounds__(64 * WMW * WNW)
void gemm_mfma(const u16* __restrict__ Ah, const u16* __restrict__ Al,
               const u16* __restrict__ Bh, const u16* __restrict__ Bl,
               const float* __restrict__ bias,
               float* __restrict__ C, int ldc, int N,
               int Kstride, int Klen, size_t c_slice,
               const float* __restrict__ Dv,
               const u16* __restrict__ xs_hi, const u16* __restrict__ xs_lo,
               const float* __restrict__ projz,
               u16* __restrict__ yg_hi, u16* __restrict__ yg_lo)
{
  constexpr int BM = 64 * WMW, BN = 64 * WNW;
  constexpr int WAVES = WMW * WNW;
  constexpr int RG_A = BM / 16, RG_B = BN / 16;
  constexpr int NG = 2 * RG_A + 2 * RG_B;
  constexpr int GPW = NG / WAVES;
  static_assert(NG % WAVES == 0, "");

  __shared__ u16 sAB[2][NG * 512];

  int bx, by, bz;
  xcd_swizzle(bx, by, bz);

  const int tid  = threadIdx.x;
  const int wave = tid >> 6;
  const int lane = tid & 63;
  const int wm   = wave % WMW;
  const int wn   = wave / WMW;
  const int bm   = bx * BM;
  const int bn   = by * BN;
  const int koff = bz * Klen;
  const int lrow = lane & 15;
  const int lkc  = lane >> 4;
  const int sr   = lane >> 2;
  const int sk8  = (lane & 3) * 8;

  const u16* gptr[GPW];
#pragma unroll
  for (int t = 0; t < GPW; ++t) {
    int g = wave * GPW + t;
    const u16* base;
    int rowbase;
    if (g < 2 * RG_A) {
      int hl = g / RG_A, i = g % RG_A;
      base = hl ? Al : Ah;  rowbase = bm + i * 16;
    } else {
      int g2 = g - 2 * RG_A;
      int hl = g2 / RG_B, i = g2 % RG_B;
      base = hl ? Bl : Bh;  rowbase = bn + i * 16;
    }
    gptr[t] = base + (size_t)(rowbase + sr) * Kstride + koff + sk8;
  }

  f32x4 acc[4][4];
#pragma unroll
  for (int i = 0; i < 4; ++i)
#pragma unroll
    for (int j = 0; j < 4; ++j) acc[i][j] = (f32x4){0.f, 0.f, 0.f, 0.f};

#define STAGE(b, kk)                                             \
  {                                                              \
    _Pragma("unroll")                                            \
    for (int t = 0; t < GPW; ++t)                                \
      gload16(gptr[t] + (kk), &sAB[b][(wave * GPW + t) * 512]);  \
  }

  STAGE(0, 0);
  asm volatile("s_waitcnt vmcnt(0)" ::: "memory");
  __syncthreads();

  int buf = 0;
  for (int k0 = 0; k0 < Klen; k0 += 32) {
    if (k0 + 32 < Klen) STAGE(buf ^ 1, k0 + 32);

    const u16* sb = sAB[buf];
    bf16x8 a_h[4], a_l[4], b_h[4], b_l[4];
#pragma unroll
    for (int i = 0; i < 4; ++i) {
      a_h[i] = *(const bf16x8*)&sb[(0 * RG_A + wm * 4 + i) * 512 + lrow * 32 + lkc * 8];
      a_l[i] = *(const bf16x8*)&sb[(1 * RG_A + wm * 4 + i) * 512 + lrow * 32 + lkc * 8];
      b_h[i] = *(const bf16x8*)&sb[(2 * RG_A + 0 * RG_B + wn * 4 + i) * 512 + lrow * 32 + lkc * 8];
      b_l[i] = *(const bf16x8*)&sb[(2 * RG_A + 1 * RG_B + wn * 4 + i) * 512 + lrow * 32 + lkc * 8];
    }
#pragma unroll
    for (int i = 0; i < 4; ++i)
#pragma unroll
      for (int j = 0; j < 4; ++j) {
        acc[i][j] = __builtin_amdgcn_mfma_f32_16x16x32_bf16(a_h[i], b_h[j], acc[i][j], 0, 0, 0);
        acc[i][j] = __builtin_amdgcn_mfma_f32_16x16x32_bf16(a_l[i], b_h[j], acc[i][j], 0, 0, 0);
        acc[i][j] = __builtin_amdgcn_mfma_f32_16x16x32_bf16(a_h[i], b_l[j], acc[i][j], 0, 0, 0);
      }

    asm volatile("s_waitcnt vmcnt(0)" ::: "memory");
    __syncthreads();
    buf ^= 1;
  }
#undef STAGE

  const int r0 = (lane >> 4) * 4;
  if (!GATE) {
    float* Cs = C + (size_t)bz * c_slice;
#pragma unroll
    for (int j = 0; j < 4; ++j) {
      int col = bn + wn * 64 + j * 16 + lrow;
      if (col >= N) continue;
      float bv = bias ? bias[col] : 0.f;
#pragma unroll
      for (int i = 0; i < 4; ++i) {
        int rowb = bm + wm * 64 + i * 16 + r0;
#pragma unroll
        for (int r = 0; r < 4; ++r)
          Cs[(size_t)(rowb + r) * ldc + col] = acc[i][j][r] + bv;
      }
    }
  } else {
#pragma unroll
    for (int j = 0; j < 4; ++j) {
      int col = bn + wn * 64 + j * 16 + lrow;     // p in [0,64)
#pragma unroll
      for (int i = 0; i < 4; ++i) {
        int rowb = bm + wm * 64 + i * 16 + r0;
#pragma unroll
        for (int r = 0; r < 4; ++r) {
          int row = rowb + r;                     // l*16 + h
          int l = row >> 4, h = row & 15;
          size_t ei = (size_t)l * 1024 + (h << 6) + col;
          float xsv = bf2f(xs_hi[ei]) + bf2f(xs_lo[ei]);
          float z = projz[(size_t)l * DPROJ + (h << 6) + col];
          float v = (acc[i][j][r] + Dv[h] * xsv) * (z / (1.f + expf(-z)));
          u16 hh = f2bf(v);
          yg_hi[ei] = hh;
          yg_lo[ei] = f2bf(v - bf2f(hh));
        }
      }
    }
  }
}

// ---------------------------------------------------------------------------
// out = sum of 4 split-K partials (float4-vectorized).
// ---------------------------------------------------------------------------
__global__ __launch_bounds__(256)
void reduce4_kernel(const float* __restrict__ p, float* __restrict__ o)
{
  const int n = L_SEQ * 512 / 4;
  int i = blockIdx.x * 256 + threadIdx.x;
  if (i >= n) return;
  float4 a = ((const float4*)p)[i];
  float4 b = ((const float4*)p)[i + n];
  float4 c = ((const float4*)p)[i + 2 * n];
  float4 d = ((const float4*)p)[i + 3 * n];
  float4 r;
  r.x = (a.x + b.x) + (c.x + d.x);
  r.y = (a.y + b.y) + (c.y + d.y);
  r.z = (a.z + b.z) + (c.z + d.z);
  r.w = (a.w + b.w) + (c.w + d.w);
  ((float4*)o)[i] = r;
}

// ---------------------------------------------------------------------------
// dt / lam in EXACT f32 straight from u . W_in rows, then coefficients.
// ---------------------------------------------------------------------------
__global__ __launch_bounds__(256)
void dtlam_kernel(const float* __restrict__ u, const float* __restrict__ W_in,
                  const float* __restrict__ b_in, const float* __restrict__ A_log,
                  float* __restrict__ dtg, float* __restrict__ alphag,
                  float* __restrict__ c0g, float* __restrict__ c1g)
{
  int idx = blockIdx.x * 256 + threadIdx.x;      // L*G = 8192
  if (idx >= L_SEQ * 4) return;
  int l = idx >> 2, g = idx & 3;
  const float4* ur = (const float4*)(u + (size_t)l * 512);
  const float4* wd = (const float4*)(W_in + (size_t)(OFF_DT + g) * 512);
  const float4* wl = (const float4*)(W_in + (size_t)(OFF_DT + 4 + g) * 512);
  float sd = 0.f, sl = 0.f;
  for (int k = 0; k < 128; ++k) {
    float4 a = ur[k], b = wd[k], c = wl[k];
    sd += a.x * b.x + a.y * b.y + a.z * b.z + a.w * b.w;
    sl += a.x * c.x + a.y * c.y + a.z * c.z + a.w * c.w;
  }
  sd += b_in[OFF_DT + g];
  sl += b_in[OFF_DT + 4 + g];
  float dt  = (sd > 20.f) ? sd : log1pf(expf(sd));
  float lam = 1.f / (1.f + expf(-sl));
  float Ag  = -expf(A_log[g]);
  float al  = expf(dt * Ag);
  dtg[idx]    = dt;
  alphag[idx] = al;
  c0g[idx]    = 1.f - lam;
  c1g[idx]    = lam * al;
}

// ---------------------------------------------------------------------------
// f64 inclusive cumsum of dt over L, per group.  grid=4 (g), block=256.
// ---------------------------------------------------------------------------
__global__ __launch_bounds__(256)
void cumsum_dt_kernel(const float* __restrict__ dtg, float* __restrict__ cumdt)
{
  const int g = blockIdx.x;
  const int t = threadIdx.x;
  constexpr int PER = L_SEQ / 256;  // 8
  __shared__ double ps[256];
  float loc[PER];
  double s = 0.0;
  int l0 = t * PER;
  for (int i = 0; i < PER; ++i) {
    loc[i] = dtg[(l0 + i) * 4 + g];
    s += (double)loc[i];
  }
  ps[t] = s;
  __syncthreads();
  for (int off = 1; off < 256; off <<= 1) {
    double v = (t >= off) ? ps[t - off] : 0.0;
    __syncthreads();
    ps[t] += v;
    __syncthreads();
  }
  double c = ps[t] - s;  // exclusive prefix
  for (int i = 0; i < PER; ++i) {
    c += (double)loc[i];
    cumdt[(l0 + i) * 4 + g] = (float)c;
  }
}

// ---------------------------------------------------------------------------
// Per-token: silu(xp) -> xs hi/lo split ; rms+bias+rope for B/C.
// ---------------------------------------------------------------------------
__global__ __launch_bounds__(256)
void pertoken_kernel(const float* __restrict__ proj,
                     const float* __restrict__ cumdt,
                     const float* __restrict__ theta_log,
                     const float* __restrict__ norm_B_w,
                     const float* __restrict__ norm_C_w,
                     const float* __restrict__ bias_B,
                     const float* __restrict__ bias_C,
                     u16* __restrict__ xs_hi, u16* __restrict__ xs_lo,
                     float* __restrict__ Brot,
                     float* __restrict__ Crot)
{
  const int l = blockIdx.x;
  const int t = threadIdx.x;
  const size_t prow = (size_t)l * DPROJ;

  for (int i = t; i < 1024; i += 256) {
    float x = proj[prow + OFF_X + i];
    float s = x / (1.f + expf(-x));
    u16 hh = f2bf(s);
    xs_hi[(size_t)l * 1024 + i] = hh;
    xs_lo[(size_t)l * 1024 + i] = f2bf(s - bf2f(hh));
  }

  const int g = t >> 6;
  const int e = t & 63;
  float bv = proj[prow + OFF_B + t];
  float cv = proj[prow + OFF_C + t];
  float ssb = bv * bv, ssc = cv * cv;
#pragma unroll
  for (int m = 1; m <= 32; m <<= 1) {
    ssb += __shfl_xor(ssb, m, 64);
    ssc += __shfl_xor(ssc, m, 64);
  }
  float nb = bv * rsqrtf(ssb * (1.f / 64.f) + 1e-5f) * norm_B_w[e] + bias_B[t];
  float nc = cv * rsqrtf(ssc * (1.f / 64.f) + 1e-5f) * norm_C_w[e] + bias_C[t];

  float ang = expf(theta_log[g * 16 + (e >> 2)]) * cumdt[l * 4 + g];
  float ca, sa;
  sincosf(ang, &sa, &ca);   // sincosf writes SIN to 1st ptr, COS to 2nd
  float nb2 = __shfl_xor(nb, 2, 64);
  float nc2 = __shfl_xor(nc, 2, 64);
  bool isre = ((e >> 1) & 1) == 0;
  float Bo, Co;
  if (isre) {
    Bo = nb * ca + nb2 * sa;   // theta = -ang
    Co = nc * ca - nc2 * sa;   // theta = +ang
  } else {
    Bo = nb * ca - nb2 * sa;
    Co = nc * ca + nc2 * sa;
  }
  Brot[(size_t)l * 256 + t] = Bo;
  Crot[(size_t)l * 256 + t] = Co;
}

// ---------------------------------------------------------------------------
// Scan: lane = p, per-thread state H[n=0..31] + uprev[n].
// grid = (NCH, G), block = 256 (4 waves = 4 heads of group g).
// WITH_Y=true writes y directly as bf16 hi/lo split.
// ---------------------------------------------------------------------------
template<bool WITH_Y>
__global__ __launch_bounds__(256)
void scan_chunk(const float* __restrict__ Brot, const float* __restrict__ Crot,
                const float* __restrict__ xup,
                const float* __restrict__ dtg, const float* __restrict__ alphag,
                const float* __restrict__ c0g, const float* __restrict__ c1g,
                const float* __restrict__ hstates_in,
                float* __restrict__ hlast_out,
                u16* __restrict__ yhi, u16* __restrict__ ylo)
{
  const int c   = blockIdx.x;
  const int g   = blockIdx.y;
  const int wid = threadIdx.x >> 6;
  const int p   = threadIdx.x & 63;
  const int h   = g * 4 + wid;
  const int l0  = c * SCHUNK;

  __shared__ float Bs[SCHUNK][64];
  __shared__ float Cs[SCHUNK][64];
  __shared__ float als[SCHUNK], c0s[SCHUNK], c1s[SCHUNK];

  for (int i = threadIdx.x; i < SCHUNK * 64; i += 256) {
    int l = i >> 6, e = i & 63;
    float dt = dtg[(l0 + l) * 4 + g];
    Bs[l][e] = dt * Brot[(size_t)(l0 + l) * 256 + g * 64 + e];
    if (WITH_Y) Cs[l][e] = Crot[(size_t)(l0 + l) * 256 + g * 64 + e];
  }
  if (threadIdx.x < SCHUNK) {
    int l = threadIdx.x;
    als[l] = alphag[(l0 + l) * 4 + g];
    c0s[l] = c0g[(l0 + l) * 4 + g];
    c1s[l] = c1g[(l0 + l) * 4 + g];
  }
  __syncthreads();

  float H[32], up[32];
  if (WITH_Y) {
    const float* hs = &hstates_in[(((size_t)c * 16 + h) * 64 + p) * 32];
#pragma unroll
    for (int q = 0; q < 8; ++q) {
      float4 v = *reinterpret_cast<const float4*>(hs + 4 * q);
      H[4 * q] = v.x; H[4 * q + 1] = v.y; H[4 * q + 2] = v.z; H[4 * q + 3] = v.w;
    }
  } else {
#pragma unroll
    for (int n = 0; n < 32; ++n) H[n] = 0.f;
  }

  if (c > 0) {
    const int lm = l0 - 1;
    const float dtm = dtg[lm * 4 + g];
    float2 X = *reinterpret_cast<const float2*>(&xup[((size_t)lm * 16 + h) * 128 + 2 * p]);
    float x0 = dtm * X.x, x1 = dtm * X.y;
#pragma unroll
    for (int n = 0; n < 32; ++n) {
      float2 Bv = *reinterpret_cast<const float2*>(&Brot[(size_t)lm * 256 + g * 64 + 2 * n]);
      up[n] = Bv.x * x0 + Bv.y * x1;
    }
  } else {
#pragma unroll
    for (int n = 0; n < 32; ++n) up[n] = 0.f;
  }

  for (int l = 0; l < SCHUNK; ++l) {
    float2 X = *reinterpret_cast<const float2*>(
        &xup[((size_t)(l0 + l) * 16 + h) * 128 + 2 * p]);
    const float al = als[l], cc0 = c0s[l], cc1 = c1s[l];
    float y0 = 0.f, y1 = 0.f;
#pragma unroll
    for (int n2 = 0; n2 < 16; ++n2) {
      float4 Bv = *reinterpret_cast<const float4*>(&Bs[l][4 * n2]);
      float uin0 = Bv.x * X.x + Bv.y * X.y;
      float uin1 = Bv.z * X.x + Bv.w * X.y;
      float ue0 = cc0 * uin0 + cc1 * up[2 * n2];
      float ue1 = cc0 * uin1 + cc1 * up[2 * n2 + 1];
      H[2 * n2]     = al * H[2 * n2]     + ue0;
      H[2 * n2 + 1] = al * H[2 * n2 + 1] + ue1;
      up[2 * n2] = uin0; up[2 * n2 + 1] = uin1;
      if (WITH_Y) {
        float4 Cv = *reinterpret_cast<const float4*>(&Cs[l][4 * n2]);
        y0 = fmaf(H[2 * n2], Cv.x, fmaf(H[2 * n2 + 1], Cv.z, y0));
        y1 = fmaf(H[2 * n2], Cv.y, fmaf(H[2 * n2 + 1], Cv.w, y1));
      }
    }
    if (WITH_Y) {
      size_t ofs = ((size_t)(l0 + l) * 16 + h) * 128 + 2 * p;
      u16 h0 = f2bf(y0), h1 = f2bf(y1);
      *(ushort2*)&yhi[ofs] = make_ushort2(h0, h1);
      *(ushort2*)&ylo[ofs] = make_ushort2(f2bf(y0 - bf2f(h0)), f2bf(y1 - bf2f(h1)));
    }
  }

  if (!WITH_Y) {
    float* hl = &hlast_out[(((size_t)c * 16 + h) * 64 + p) * 32];
#pragma unroll
    for (int q = 0; q < 8; ++q)
      *reinterpret_cast<float4*>(hl + 4 * q) =
          make_float4(H[4 * q], H[4 * q + 1], H[4 * q + 2], H[4 * q + 3]);
  }
}

// ---------------------------------------------------------------------------
// Scan pass B: cross-chunk combine -> h_states (state entering each chunk).
// ---------------------------------------------------------------------------
__global__ __launch_bounds__(256)
void scan_passB(const float* __restrict__ hlast, const float* __restrict__ cumdt,
                const float* __restrict__ A_log, float* __restrict__ hstates)
{
  int idx = blockIdx.x * 256 + threadIdx.x;   // H * P * N = 32768
  int h = idx >> 11;
  int rem = idx & 2047;
  int g = h >> 2;
  float Ag = -expf(A_log[g]);
  float s = 0.f;
  for (int c = 0; c < NCH; ++c) {
    hstates[((size_t)c * 16 + h) * 2048 + rem] = s;
    float sd = cumdt[(c * SCHUNK + SCHUNK - 1) * 4 + g]
             - (c > 0 ? cumdt[(c * SCHUNK - 1) * 4 + g] : 0.f);
    float dec = expf(Ag * sd);
    s = s * dec + hlast[((size_t)c * 16 + h) * 2048 + rem];
  }
}

}  // namespace

extern "C" void kernel_launch(void* const* d_in, const int* in_sizes, int n_in,
                              void* d_out, int out_size, void* d_ws, size_t ws_size,
                              hipStream_t stream)
{
  const float* u         = (const float*)d_in[0];
  const float* W_in      = (const float*)d_in[1];
  const float* b_in      = (const float*)d_in[2];
  const float* W_xup     = (const float*)d_in[3];
  const float* W_ydown   = (const float*)d_in[4];
  const float* A_log     = (const float*)d_in[5];
  const float* theta_log = (const float*)d_in[6];
  const float* Dvec      = (const float*)d_in[7];
  const float* norm_B_w  = (const float*)d_in[8];
  const float* norm_C_w  = (const float*)d_in[9];
  const float* bias_B    = (const float*)d_in[10];
  const float* bias_C    = (const float*)d_in[11];
  const float* W_out     = (const float*)d_in[12];
  float* out = (float*)d_out;

  // ---- f32 workspace carve (floats) ----
  float* proj    = (float*)d_ws;                    // 2048*2568
  float* xsreg   = proj    + (size_t)L_SEQ * DPROJ; // 2048*1024 floats (holds xs hi+lo u16)
  float* dtg     = xsreg   + (size_t)L_SEQ * 1024;  // 2048*4 each
  float* alphag  = dtg     + L_SEQ * 4;
  float* c0g     = alphag  + L_SEQ * 4;
  float* c1g     = c0g     + L_SEQ * 4;
  float* cumdt   = c1g     + L_SEQ * 4;
  float* Brot    = cumdt   + L_SEQ * 4;             // 2048*256
  float* Crot    = Brot    + (size_t)L_SEQ * 256;
  float* xup     = Crot    + (size_t)L_SEQ * 256;   // 32768*128
  float* y128s   = xup     + (size_t)32768 * 128;   // slot: 32768*128 floats
  float* yds     = y128s   + (size_t)32768 * 128;   // slot: 32768*64 floats
  float* hlast   = y128s;                           // alias (dead before y-writes)
  float* hstates = yds;                             // alias
  float* partials = y128s;                          // alias (y128 bf16 dead by out gemm)

  // xs hi/lo live in the xsreg slot (u16 planes)
  u16* xs_hi = (u16*)xsreg;
  u16* xs_lo = xs_hi + (size_t)L_SEQ * 1024;
  // y128 hi/lo live in the y128s slot
  u16* y128_hi = (u16*)y128s;
  u16* y128_lo = y128_hi + (size_t)32768 * 128;

  // ---- bf16 hi/lo region A (u16), phase-overlaid ----
  u16* rA = (u16*)(yds + (size_t)32768 * 64);
  // phase 1: proj gemm operands
  u16* u_hi   = rA;
  u16* u_lo   = u_hi + (size_t)2048 * 512;
  u16* win_hi = u_lo + (size_t)2048 * 512;          // padded to 2688 rows
  u16* win_lo = win_hi + (size_t)2688 * 512;
  // phase 2: xup weights (tiny, after phase-1 area)
  u16* wxup_hi = rA;
  u16* wxup_lo = wxup_hi + (size_t)128 * 64;
  // phase 3/4: ydown weights + yg + wout (sequential, non-overlapping)
  u16* wyd_hi  = rA + (size_t)64 * 1024;            // after wxup (keep wxup alive til xup gemm)
  u16* wyd_lo  = wyd_hi + (size_t)64 * 128;
  u16* yg_hi   = wyd_lo + (size_t)64 * 128;
  u16* yg_lo   = yg_hi + (size_t)2048 * 1024;
  u16* wout_hi = yg_lo + (size_t)2048 * 1024;
  u16* wout_lo = wout_hi + (size_t)512 * 1024;

  // 1. convert u, W_in -> split bf16 ; proj = u @ W_in^T + b_in (MFMA)
  convert_split<<<dim3(1024), 256, 0, stream>>>(u, 2048, 512, 512, 2048, u_hi, u_lo);
  convert_split<<<dim3(1344), 256, 0, stream>>>(W_in, 2568, 512, 512, 2688, win_hi, win_lo);
  gemm_mfma<2, 2, false><<<dim3(16, 21, 1), 256, 0, stream>>>(
      u_hi, u_lo, win_hi, win_lo, b_in, proj, DPROJ, DPROJ, 512, 512, 0,
      nullptr, nullptr, nullptr, nullptr, nullptr, nullptr);

  // 2. dt/lam exact-f32; 3. f64 cumsum
  dtlam_kernel<<<dim3(32), 256, 0, stream>>>(u, W_in, b_in, A_log, dtg, alphag, c0g, c1g);
  cumsum_dt_kernel<<<dim3(4), 256, 0, stream>>>(dtg, cumdt);

  // 4. per-token: silu(xp) -> xs hi/lo, rms+bias+rope -> Brot/Crot
  pertoken_kernel<<<dim3(L_SEQ), 256, 0, stream>>>(
      proj, cumdt, theta_log, norm_B_w, norm_C_w, bias_B, bias_C,
      xs_hi, xs_lo, Brot, Crot);

  // 5. x_up = xs @ W_xup^T (MFMA) -- phase-1 rA data dead now
  convert_split<<<dim3(8), 256, 0, stream>>>(W_xup, 128, 64, 64, 128, wxup_hi, wxup_lo);
  gemm_mfma<2, 2, false><<<dim3(256, 1, 1), 256, 0, stream>>>(
      xs_hi, xs_lo, wxup_hi, wxup_lo, nullptr, xup, 128, 128, 64, 64, 0,
      nullptr, nullptr, nullptr, nullptr, nullptr, nullptr);

  // 6-8. chunked scan (state-in-registers); scanC emits y128 bf16 hi/lo
  scan_chunk<false><<<dim3(NCH, 4), 256, 0, stream>>>(
      Brot, Crot, xup, dtg, alphag, c0g, c1g, nullptr, hlast, nullptr, nullptr);
  scan_passB<<<dim3(128), 256, 0, stream>>>(hlast, cumdt, A_log, hstates);
  scan_chunk<true><<<dim3(NCH, 4), 256, 0, stream>>>(
      Brot, Crot, xup, dtg, alphag, c0g, c1g, hstates, nullptr, y128_hi, y128_lo);

  // 9+10. ydown GEMM with fused gate epilogue -> yg hi/lo directly
  convert_split<<<dim3(8), 256, 0, stream>>>(W_ydown, 64, 128, 128, 64, wyd_hi, wyd_lo);
  gemm_mfma<2, 1, true><<<dim3(256, 1, 1), 128, 0, stream>>>(
      y128_hi, y128_lo, wyd_hi, wyd_lo, nullptr, nullptr, 0, 64, 128, 128, 0,
      Dvec, xs_hi, xs_lo, proj, yg_hi, yg_lo);

  // 11. out = yg @ W_out^T (MFMA, split-K=4 into partials) ; reduce
  convert_split<<<dim3(512), 256, 0, stream>>>(W_out, 512, 1024, 1024, 512, wout_hi, wout_lo);
  gemm_mfma<2, 2, false><<<dim3(16, 4, 4), 256, 0, stream>>>(
      yg_hi, yg_lo, wout_hi, wout_lo, nullptr, partials, 512, 512, 1024, 256,
      (size_t)L_SEQ * 512,
      nullptr, nullptr, nullptr, nullptr, nullptr, nullptr);
  reduce4_kernel<<<dim3(1024), 256, 0, stream>>>(partials, out);
}